// Round 19
// baseline (195.075 us; speedup 1.0000x reference)
//
#include <hip/hip_runtime.h>

#define NN 100000
#define NE 1600000

typedef __attribute__((ext_vector_type(16))) int i32x16;

// ---- bucketed CSR build ----
// bucket = dst >> 8  (256 nodes per bucket)
#define NBKT 391                 // ceil(100000 / 256)
#define NBLK 256                 // partition blocks
#define EPB  (NE / NBLK)         // 6250 edges per partition block
#define PTH  512                 // threads in partition/bucket kernels
#define TOT  (NBKT * NBLK)       // 100096 pcount entries
#define SB   ((TOT + 1023) / 1024)  // 98 scan blocks

__global__ __launch_bounds__(PTH) void k_pcount(const int* __restrict__ dst,
                                                int* __restrict__ pcount) {
  __shared__ int lcnt[NBKT];
  int t = threadIdx.x, b = blockIdx.x;
  for (int i = t; i < NBKT; i += PTH) lcnt[i] = 0;
  __syncthreads();
  int base = b * EPB;
  for (int i = t; i < EPB; i += PTH)
    atomicAdd(&lcnt[dst[base + i] >> 8], 1);
  __syncthreads();
  for (int i = t; i < NBKT; i += PTH)
    pcount[i * NBLK + b] = lcnt[i];   // bucket-major layout
}

// hierarchical exclusive scan of pcount[TOT]
__global__ __launch_bounds__(256) void k_pscan1(int* __restrict__ pcount,
                                                int* __restrict__ bsum) {
  __shared__ int sh[256];
  int t = threadIdx.x, b = blockIdx.x;
  int base = b * 1024 + t * 4;
  int v0 = (base + 0 < TOT) ? pcount[base + 0] : 0;
  int v1 = (base + 1 < TOT) ? pcount[base + 1] : 0;
  int v2 = (base + 2 < TOT) ? pcount[base + 2] : 0;
  int v3 = (base + 3 < TOT) ? pcount[base + 3] : 0;
  int s = v0 + v1 + v2 + v3;
  sh[t] = s;
  __syncthreads();
  for (int off = 1; off < 256; off <<= 1) {
    int x = (t >= off) ? sh[t - off] : 0;
    __syncthreads();
    sh[t] += x;
    __syncthreads();
  }
  int ex = sh[t] - s;
  if (t == 255) bsum[b] = sh[255];
  if (base + 0 < TOT) pcount[base + 0] = ex; ex += v0;
  if (base + 1 < TOT) pcount[base + 1] = ex; ex += v1;
  if (base + 2 < TOT) pcount[base + 2] = ex; ex += v2;
  if (base + 3 < TOT) pcount[base + 3] = ex;
}

__global__ __launch_bounds__(128) void k_pscan2(int* __restrict__ bsum) {
  __shared__ int sh[128];
  int t = threadIdx.x;
  int v = (t < SB) ? bsum[t] : 0;
  sh[t] = v;
  __syncthreads();
  for (int off = 1; off < 128; off <<= 1) {
    int x = (t >= off) ? sh[t - off] : 0;
    __syncthreads();
    sh[t] += x;
    __syncthreads();
  }
  if (t < SB) bsum[t] = sh[t] - v;  // exclusive
}

__global__ __launch_bounds__(256) void k_pscan3(int* __restrict__ pcount,
                                                const int* __restrict__ bsum) {
  int t = threadIdx.x, b = blockIdx.x;
  int add = bsum[b];
  int base = b * 1024 + t * 4;
  #pragma unroll
  for (int k = 0; k < 4; ++k)
    if (base + k < TOT) pcount[base + k] += add;
}

// staged entry packs src (17 bits) | (dst & 255) << 17
__global__ __launch_bounds__(PTH) void k_pscatter(const int* __restrict__ src,
                                                  const int* __restrict__ dst,
                                                  const int* __restrict__ pcount,
                                                  int* __restrict__ staged) {
  __shared__ int lpos[NBKT];
  int t = threadIdx.x, b = blockIdx.x;
  for (int i = t; i < NBKT; i += PTH) lpos[i] = pcount[i * NBLK + b];
  __syncthreads();
  int base = b * EPB;
  for (int i = t; i < EPB; i += PTH) {
    int s = src[base + i], d = dst[base + i];
    int pos = atomicAdd(&lpos[d >> 8], 1);
    staged[pos] = s | ((d & 255) << 17);
  }
}

__global__ __launch_bounds__(PTH) void k_bucket(const int* __restrict__ staged,
                                                const int* __restrict__ pcount,
                                                int* __restrict__ rowptr,
                                                float* __restrict__ dis,
                                                int* __restrict__ col) {
  __shared__ int lcnt[256];
  __shared__ int lscan[PTH];
  __shared__ int lpos[256];
  int t = threadIdx.x, bkt = blockIdx.x;
  int sbeg = pcount[bkt * NBLK];
  int send = (bkt == NBKT - 1) ? NE : pcount[(bkt + 1) * NBLK];

  if (t < 256) lcnt[t] = 0;
  __syncthreads();
  for (int i = sbeg + t; i < send; i += PTH)
    atomicAdd(&lcnt[(unsigned)staged[i] >> 17], 1);
  __syncthreads();

  int v = (t < 256) ? lcnt[t] : 0;
  lscan[t] = v;
  __syncthreads();
  for (int off = 1; off < PTH; off <<= 1) {
    int x = (t >= off) ? lscan[t - off] : 0;
    __syncthreads();
    lscan[t] += x;
    __syncthreads();
  }
  if (t < 256) {
    int gbase = sbeg + lscan[t] - v;
    int node = bkt * 256 + t;
    if (node < NN) {
      rowptr[node] = gbase;
      dis[node] = rsqrtf((float)(v + 1));  // +1 self-loop
    }
    lpos[t] = gbase;
    if (bkt == NBKT - 1 && t == 0) rowptr[NN] = NE;
  }
  __syncthreads();

  for (int i = sbeg + t; i < send; i += PTH) {
    int e = staged[i];
    col[atomicAdd(&lpos[(unsigned)e >> 17], 1)] = e & 0x1FFFF;
  }
}

__device__ __forceinline__ unsigned bf16rne(float x) {
  unsigned u = __float_as_uint(x);
  return (u + 0x7fffu + ((u >> 16) & 1u)) >> 16;   // round-nearest-even
}

// ---- layer 1 transform: t' = dis * (x @ W), bf16 [NN][64] ----
__global__ __launch_bounds__(256) void k_xform(const float* __restrict__ h,
                                               const float* __restrict__ W,
                                               const float* __restrict__ dis,
                                               unsigned short* __restrict__ ts) {
  __shared__ float hT[64][132];  // [k][row]
  __shared__ float Wl[64][68];   // [k][col]
  const int tid = threadIdx.x;
  const int R0 = blockIdx.x * 128;

  {
    const float4* W4 = (const float4*)W;
    #pragma unroll
    for (int j = 0; j < 4; ++j) {
      int idx = tid + 256 * j;
      float4 v = W4[idx];
      int k = idx >> 4;
      int c = (idx & 15) * 4;
      Wl[k][c + 0] = v.x; Wl[k][c + 1] = v.y;
      Wl[k][c + 2] = v.z; Wl[k][c + 3] = v.w;
    }
  }
  {
    #pragma unroll
    for (int j = 0; j < 8; ++j) {
      int idx = tid + 256 * j;
      int r = idx >> 4;
      int k = (idx & 15) * 4;
      int rg = R0 + r; if (rg > NN - 1) rg = NN - 1;
      float4 v = *(const float4*)(h + (size_t)rg * 64 + k);
      hT[k + 0][r] = v.x; hT[k + 1][r] = v.y;
      hT[k + 2][r] = v.z; hT[k + 3][r] = v.w;
    }
  }
  __syncthreads();

  const int tx = tid & 7;
  const int ty = tid >> 3;
  float acc[4][8];
  #pragma unroll
  for (int i = 0; i < 4; ++i)
    #pragma unroll
    for (int j = 0; j < 8; ++j) acc[i][j] = 0.f;

  #pragma unroll 4
  for (int k = 0; k < 64; ++k) {
    float4 hv = *(const float4*)&hT[k][ty * 4];
    float4 w0 = *(const float4*)&Wl[k][tx * 8];
    float4 w1 = *(const float4*)&Wl[k][tx * 8 + 4];
    float hh[4] = {hv.x, hv.y, hv.z, hv.w};
    float wc[8] = {w0.x, w0.y, w0.z, w0.w, w1.x, w1.y, w1.z, w1.w};
    #pragma unroll
    for (int i = 0; i < 4; ++i)
      #pragma unroll
      for (int j = 0; j < 8; ++j)
        acc[i][j] = fmaf(hh[i], wc[j], acc[i][j]);
  }

  #pragma unroll
  for (int i = 0; i < 4; ++i) {
    int r = R0 + ty * 4 + i;
    if (r < NN) {
      float dr = dis[r];
      uint4 pk;
      pk.x = bf16rne(acc[i][0] * dr) | (bf16rne(acc[i][1] * dr) << 16);
      pk.y = bf16rne(acc[i][2] * dr) | (bf16rne(acc[i][3] * dr) << 16);
      pk.z = bf16rne(acc[i][4] * dr) | (bf16rne(acc[i][5] * dr) << 16);
      pk.w = bf16rne(acc[i][6] * dr) | (bf16rne(acc[i][7] * dr) << 16);
      *(uint4*)(ts + (size_t)r * 64 + tx * 8) = pk;
    }
  }
}

// ---- fused: h' = relu(dis_d*(S_sum t') + b) ; t_next = dis * (h' @ Wn) ----
// v3: block = 64 nodes, wave gathers 16 (two 8-node halves, registers stay
// at the proven a[8][4]); h' -> hh[64][68] row-major. Phase 2: 2 rows x
// 8 cols per thread, hh read float4-over-k -> 2x output rows per LDS cycle.
// Each wave reads only its own hh rows, so no barrier before phase 2.
__global__ __launch_bounds__(256) void k_fuse(
    const unsigned short* __restrict__ ts, const int* __restrict__ rowptr,
    const int* __restrict__ col, const float* __restrict__ dis,
    const float* __restrict__ bias, const float* __restrict__ Wn,
    unsigned short* __restrict__ tnext)
{
  __shared__ float Wl[64][68];
  __shared__ float hh[64][68];
  const int tid  = threadIdx.x;
  const int lane = tid & 63;
  const int slot = lane >> 4;
  const int fq   = lane & 15;
  const int R0   = blockIdx.x * 64;
  const int wloc = tid >> 6;            // wave in block 0..3
  const int wbase = __builtin_amdgcn_readfirstlane(R0 + wloc * 16);

  // stage Wn
  {
    const float4* W4 = (const float4*)Wn;
    #pragma unroll
    for (int j = 0; j < 4; ++j) {
      int idx = tid + 256 * j;
      float4 v = W4[idx];
      int k = idx >> 4;
      int c = (idx & 15) * 4;
      Wl[k][c + 0] = v.x; Wl[k][c + 1] = v.y;
      Wl[k][c + 2] = v.z; Wl[k][c + 3] = v.w;
    }
  }
  __syncthreads();   // Wl visible to all waves (the only barrier)

  const float4 bv = *(const float4*)(bias + fq * 4);
  const float m_self = (slot == 0) ? 1.f : 0.f;

  #pragma unroll 2
  for (int half = 0; half < 2; ++half) {
    const int n0 = wbase + half * 8;
    if (n0 < NN) {
      i32x16 rp;
      asm volatile("s_load_dwordx16 %0, %1, 0x0\n\ts_waitcnt lgkmcnt(0)"
                   : "=s"(rp) : "s"(rowptr + n0));

      float a[8][4];
      #pragma unroll
      for (int i = 0; i < 8; ++i) {
        const uint2 sv = *(const uint2*)(ts + (size_t)(n0 + i) * 64 + fq * 4);
        a[i][0] = m_self * __uint_as_float(sv.x << 16);
        a[i][1] = m_self * __uint_as_float(sv.x & 0xffff0000u);
        a[i][2] = m_self * __uint_as_float(sv.y << 16);
        a[i][3] = m_self * __uint_as_float(sv.y & 0xffff0000u);
      }

      // phase 1a: first 16 edges of each node, straight-line & masked
      #pragma unroll
      for (int i = 0; i < 8; ++i) {
        const int r0 = rp[i], r1 = rp[i + 1];
        #pragma unroll
        for (int s = 0; s < 4; ++s) {
          int e = r0 + s * 4 + slot;
          int c = col[e];
          bool valid = e < r1;
          c = valid ? c : 0;
          float m = valid ? 1.f : 0.f;
          const uint2 gv = *(const uint2*)(ts + (size_t)c * 64 + fq * 4);
          a[i][0] = fmaf(m, __uint_as_float(gv.x << 16),         a[i][0]);
          a[i][1] = fmaf(m, __uint_as_float(gv.x & 0xffff0000u), a[i][1]);
          a[i][2] = fmaf(m, __uint_as_float(gv.y << 16),         a[i][2]);
          a[i][3] = fmaf(m, __uint_as_float(gv.y & 0xffff0000u), a[i][3]);
        }
      }

      // phase 1b: remainders (deg > 16)
      #pragma unroll
      for (int i = 0; i < 8; ++i) {
        const int r1 = rp[i + 1];
        #pragma unroll 1
        for (int e0 = rp[i] + 16; e0 < r1; e0 += 8) {
          #pragma unroll
          for (int s = 0; s < 2; ++s) {
            int e = e0 + s * 4 + slot;
            int c = col[e];
            bool valid = e < r1;
            c = valid ? c : 0;
            float m = valid ? 1.f : 0.f;
            const uint2 gv = *(const uint2*)(ts + (size_t)c * 64 + fq * 4);
            a[i][0] = fmaf(m, __uint_as_float(gv.x << 16),         a[i][0]);
            a[i][1] = fmaf(m, __uint_as_float(gv.x & 0xffff0000u), a[i][1]);
            a[i][2] = fmaf(m, __uint_as_float(gv.y << 16),         a[i][2]);
            a[i][3] = fmaf(m, __uint_as_float(gv.y & 0xffff0000u), a[i][3]);
          }
        }
      }

      // reduce across slots; h' = relu(dn*s + b) -> hh (own wave's rows)
      #pragma unroll
      for (int i = 0; i < 8; ++i) {
        const int node = n0 + i;
        const float dn = dis[node];
        float s0 = a[i][0], s1 = a[i][1], s2 = a[i][2], s3 = a[i][3];
        s0 += __shfl_xor(s0, 16); s1 += __shfl_xor(s1, 16);
        s2 += __shfl_xor(s2, 16); s3 += __shfl_xor(s3, 16);
        s0 += __shfl_xor(s0, 32); s1 += __shfl_xor(s1, 32);
        s2 += __shfl_xor(s2, 32); s3 += __shfl_xor(s3, 32);
        float4 o;
        o.x = fmaxf(fmaf(dn, s0, bv.x), 0.f);
        o.y = fmaxf(fmaf(dn, s1, bv.y), 0.f);
        o.z = fmaxf(fmaf(dn, s2, bv.z), 0.f);
        o.w = fmaxf(fmaf(dn, s3, bv.w), 0.f);
        if (lane < 16)
          *(float4*)&hh[wloc * 16 + half * 8 + i][fq * 4] = o;
      }
    }
  }

  // phase 2 (no barrier: wave reads only rows it wrote):
  // thread = 2 rows x 8 cols; hh read as float4 over k.
  const int cg = lane & 7;           // col group
  const int lr = wloc * 16 + (lane >> 3) * 2;   // local rows lr, lr+1
  float acc[2][8];
  #pragma unroll
  for (int i = 0; i < 2; ++i)
    #pragma unroll
    for (int j = 0; j < 8; ++j) acc[i][j] = 0.f;

  #pragma unroll 2
  for (int kk = 0; kk < 16; ++kk) {
    float4 h0 = *(const float4*)&hh[lr][kk * 4];
    float4 h1 = *(const float4*)&hh[lr + 1][kk * 4];
    float h0a[4] = {h0.x, h0.y, h0.z, h0.w};
    float h1a[4] = {h1.x, h1.y, h1.z, h1.w};
    #pragma unroll
    for (int j4 = 0; j4 < 4; ++j4) {
      const int k = kk * 4 + j4;
      float4 w0 = *(const float4*)&Wl[k][cg * 8];
      float4 w1 = *(const float4*)&Wl[k][cg * 8 + 4];
      float wc[8] = {w0.x, w0.y, w0.z, w0.w, w1.x, w1.y, w1.z, w1.w};
      #pragma unroll
      for (int j = 0; j < 8; ++j) {
        acc[0][j] = fmaf(h0a[j4], wc[j], acc[0][j]);
        acc[1][j] = fmaf(h1a[j4], wc[j], acc[1][j]);
      }
    }
  }

  #pragma unroll
  for (int i = 0; i < 2; ++i) {
    const int r = R0 + (lr - R0 % 64) + i;   // == R0 + local row + i
    const int rr = R0 + (wloc * 16 + (lane >> 3) * 2) + i;
    if (rr < NN) {
      float dr = dis[rr];
      uint4 pk;
      pk.x = bf16rne(acc[i][0] * dr) | (bf16rne(acc[i][1] * dr) << 16);
      pk.y = bf16rne(acc[i][2] * dr) | (bf16rne(acc[i][3] * dr) << 16);
      pk.z = bf16rne(acc[i][4] * dr) | (bf16rne(acc[i][5] * dr) << 16);
      pk.w = bf16rne(acc[i][6] * dr) | (bf16rne(acc[i][7] * dr) << 16);
      *(uint4*)(tnext + (size_t)rr * 64 + cg * 8) = pk;
    }
    (void)r;
  }
}

// ---- final layer: out = dis_d*(S_sum t') + b  (fp32, no relu) ----
__global__ __launch_bounds__(256) void k_agg(
    const unsigned short* __restrict__ ts, const int* __restrict__ rowptr,
    const int* __restrict__ col, const float* __restrict__ dis,
    const float* __restrict__ bias, float* __restrict__ out)
{
  const int lane = threadIdx.x & 63;
  const int slot = lane >> 4;
  const int fq   = lane & 15;
  const int wid  = __builtin_amdgcn_readfirstlane(
                     (int)((blockIdx.x * blockDim.x + threadIdx.x) >> 6));
  const int n0   = wid * 8;
  if (n0 >= NN) return;

  const float4 bv = *(const float4*)(bias + fq * 4);
  const float m_self = (slot == 0) ? 1.f : 0.f;

  i32x16 rp;
  asm volatile("s_load_dwordx16 %0, %1, 0x0\n\ts_waitcnt lgkmcnt(0)"
               : "=s"(rp) : "s"(rowptr + n0));

  float a[8][4];
  #pragma unroll
  for (int i = 0; i < 8; ++i) {
    const uint2 sv = *(const uint2*)(ts + (size_t)(n0 + i) * 64 + fq * 4);
    a[i][0] = m_self * __uint_as_float(sv.x << 16);
    a[i][1] = m_self * __uint_as_float(sv.x & 0xffff0000u);
    a[i][2] = m_self * __uint_as_float(sv.y << 16);
    a[i][3] = m_self * __uint_as_float(sv.y & 0xffff0000u);
  }

  #pragma unroll
  for (int i = 0; i < 8; ++i) {
    const int r0 = rp[i], r1 = rp[i + 1];
    #pragma unroll
    for (int s = 0; s < 4; ++s) {
      int e = r0 + s * 4 + slot;
      int c = col[e];
      bool valid = e < r1;
      c = valid ? c : 0;
      float m = valid ? 1.f : 0.f;
      const uint2 gv = *(const uint2*)(ts + (size_t)c * 64 + fq * 4);
      a[i][0] = fmaf(m, __uint_as_float(gv.x << 16),         a[i][0]);
      a[i][1] = fmaf(m, __uint_as_float(gv.x & 0xffff0000u), a[i][1]);
      a[i][2] = fmaf(m, __uint_as_float(gv.y << 16),         a[i][2]);
      a[i][3] = fmaf(m, __uint_as_float(gv.y & 0xffff0000u), a[i][3]);
    }
  }

  #pragma unroll
  for (int i = 0; i < 8; ++i) {
    const int r1 = rp[i + 1];
    #pragma unroll 1
    for (int e0 = rp[i] + 16; e0 < r1; e0 += 8) {
      #pragma unroll
      for (int s = 0; s < 2; ++s) {
        int e = e0 + s * 4 + slot;
        int c = col[e];
        bool valid = e < r1;
        c = valid ? c : 0;
        float m = valid ? 1.f : 0.f;
        const uint2 gv = *(const uint2*)(ts + (size_t)c * 64 + fq * 4);
        a[i][0] = fmaf(m, __uint_as_float(gv.x << 16),         a[i][0]);
        a[i][1] = fmaf(m, __uint_as_float(gv.x & 0xffff0000u), a[i][1]);
        a[i][2] = fmaf(m, __uint_as_float(gv.y << 16),         a[i][2]);
        a[i][3] = fmaf(m, __uint_as_float(gv.y & 0xffff0000u), a[i][3]);
      }
    }
  }

  #pragma unroll
  for (int i = 0; i < 8; ++i) {
    const int node = n0 + i;
    const float dn = dis[node];
    float s0 = a[i][0], s1 = a[i][1], s2 = a[i][2], s3 = a[i][3];
    s0 += __shfl_xor(s0, 16); s1 += __shfl_xor(s1, 16);
    s2 += __shfl_xor(s2, 16); s3 += __shfl_xor(s3, 16);
    s0 += __shfl_xor(s0, 32); s1 += __shfl_xor(s1, 32);
    s2 += __shfl_xor(s2, 32); s3 += __shfl_xor(s3, 32);
    float4 o;
    o.x = fmaf(dn, s0, bv.x); o.y = fmaf(dn, s1, bv.y);
    o.z = fmaf(dn, s2, bv.z); o.w = fmaf(dn, s3, bv.w);
    if (lane < 16)
      *(float4*)(out + (size_t)node * 64 + fq * 4) = o;
  }
}

extern "C" void kernel_launch(void* const* d_in, const int* in_sizes, int n_in,
                              void* d_out, int out_size, void* d_ws, size_t ws_size,
                              hipStream_t stream) {
  const float* x  = (const float*)d_in[0];
  const int*   ei = (const int*)d_in[1];
  const float* W1 = (const float*)d_in[2];
  const float* b1 = (const float*)d_in[3];
  const float* W2 = (const float*)d_in[4];
  const float* b2 = (const float*)d_in[5];
  const float* W3 = (const float*)d_in[6];
  const float* b3 = (const float*)d_in[7];
  float* out = (float*)d_out;

  const int* src = ei;        // edge_index[0]
  const int* dst = ei + NE;   // edge_index[1]

  char* ws = (char*)d_ws;
  size_t off = 0;
  auto alloc = [&](size_t bytes) {
    void* p = ws + off;
    off = (off + bytes + 255) & ~(size_t)255;
    return p;
  };
  int*   pcount = (int*)alloc((size_t)TOT * 4);
  int*   bsum   = (int*)alloc((size_t)SB * 4);
  int*   rowptr = (int*)alloc((size_t)(NN + 1 + 16) * 4); // +16: s_load overrun pad
  float* dis    = (float*)alloc((size_t)NN * 4);
  int*   staged = (int*)alloc((size_t)NE * 4);            // packed src|dst8
  int*   col    = (int*)alloc((size_t)(NE + 64) * 4);     // +64: load overrun pad
  unsigned short* tb1 =
      (unsigned short*)alloc((size_t)NN * 64 * 2);        // bf16 [NN][64]
  unsigned short* tb2 =
      (unsigned short*)alloc((size_t)NN * 64 * 2);        // bf16 [NN][64]
  (void)ws_size; (void)in_sizes; (void)n_in; (void)out_size;

  k_pcount  <<<NBLK, PTH, 0, stream>>>(dst, pcount);
  k_pscan1  <<<SB, 256, 0, stream>>>(pcount, bsum);
  k_pscan2  <<<1, 128, 0, stream>>>(bsum);
  k_pscan3  <<<SB, 256, 0, stream>>>(pcount, bsum);
  k_pscatter<<<NBLK, PTH, 0, stream>>>(src, dst, pcount, staged);
  k_bucket  <<<NBKT, PTH, 0, stream>>>(staged, pcount, rowptr, dis, col);

  const int XF_BLOCKS = (NN + 127) / 128;   // 782
  const int FU_BLOCKS = (NN + 63) / 64;     // 1563
  const int AG_BLOCKS = NN / 32;            // 3125 (8 nodes/wave, 4 waves)

  k_xform<<<XF_BLOCKS, 256, 0, stream>>>(x, W1, dis, tb1);
  k_fuse <<<FU_BLOCKS, 256, 0, stream>>>(tb1, rowptr, col, dis, b1, W2, tb2);
  k_fuse <<<FU_BLOCKS, 256, 0, stream>>>(tb2, rowptr, col, dis, b2, W3, tb1);
  k_agg  <<<AG_BLOCKS, 256, 0, stream>>>(tb1, rowptr, col, dis, b3, out);
}

// Round 20
// 170.503 us; speedup vs baseline: 1.1441x; 1.1441x over previous
//
#include <hip/hip_runtime.h>

#define NN 100000
#define NE 1600000

typedef __attribute__((ext_vector_type(16))) int i32x16;
typedef _Float16 f16x2 __attribute__((ext_vector_type(2)));

// f32 += dot(packed f16 pair, packed f16 pair)
__device__ __forceinline__ float dot2(unsigned h, unsigned w, float c) {
  f16x2 a = __builtin_bit_cast(f16x2, h);
  f16x2 b = __builtin_bit_cast(f16x2, w);
#if __has_builtin(__builtin_amdgcn_fdot2)
  return __builtin_amdgcn_fdot2(a, b, c, false);
#else
  return fmaf((float)a.x, (float)b.x, fmaf((float)a.y, (float)b.y, c));
#endif
}

__device__ __forceinline__ unsigned packf16(float lo, float hi) {
  f16x2 v = {(_Float16)lo, (_Float16)hi};
  return __builtin_bit_cast(unsigned, v);
}

// ---- bucketed CSR build ----
// bucket = dst >> 8  (256 nodes per bucket)
#define NBKT 391                 // ceil(100000 / 256)
#define NBLK 256                 // partition blocks
#define EPB  (NE / NBLK)         // 6250 edges per partition block
#define PTH  512                 // threads in partition/bucket kernels
#define TOT  (NBKT * NBLK)       // 100096 pcount entries
#define SB   ((TOT + 1023) / 1024)  // 98 scan blocks

__global__ __launch_bounds__(PTH) void k_pcount(const int* __restrict__ dst,
                                                int* __restrict__ pcount) {
  __shared__ int lcnt[NBKT];
  int t = threadIdx.x, b = blockIdx.x;
  for (int i = t; i < NBKT; i += PTH) lcnt[i] = 0;
  __syncthreads();
  int base = b * EPB;
  for (int i = t; i < EPB; i += PTH)
    atomicAdd(&lcnt[dst[base + i] >> 8], 1);
  __syncthreads();
  for (int i = t; i < NBKT; i += PTH)
    pcount[i * NBLK + b] = lcnt[i];   // bucket-major layout
}

// hierarchical exclusive scan of pcount[TOT]
__global__ __launch_bounds__(256) void k_pscan1(int* __restrict__ pcount,
                                                int* __restrict__ bsum) {
  __shared__ int sh[256];
  int t = threadIdx.x, b = blockIdx.x;
  int base = b * 1024 + t * 4;
  int v0 = (base + 0 < TOT) ? pcount[base + 0] : 0;
  int v1 = (base + 1 < TOT) ? pcount[base + 1] : 0;
  int v2 = (base + 2 < TOT) ? pcount[base + 2] : 0;
  int v3 = (base + 3 < TOT) ? pcount[base + 3] : 0;
  int s = v0 + v1 + v2 + v3;
  sh[t] = s;
  __syncthreads();
  for (int off = 1; off < 256; off <<= 1) {
    int x = (t >= off) ? sh[t - off] : 0;
    __syncthreads();
    sh[t] += x;
    __syncthreads();
  }
  int ex = sh[t] - s;
  if (t == 255) bsum[b] = sh[255];
  if (base + 0 < TOT) pcount[base + 0] = ex; ex += v0;
  if (base + 1 < TOT) pcount[base + 1] = ex; ex += v1;
  if (base + 2 < TOT) pcount[base + 2] = ex; ex += v2;
  if (base + 3 < TOT) pcount[base + 3] = ex;
}

__global__ __launch_bounds__(128) void k_pscan2(int* __restrict__ bsum) {
  __shared__ int sh[128];
  int t = threadIdx.x;
  int v = (t < SB) ? bsum[t] : 0;
  sh[t] = v;
  __syncthreads();
  for (int off = 1; off < 128; off <<= 1) {
    int x = (t >= off) ? sh[t - off] : 0;
    __syncthreads();
    sh[t] += x;
    __syncthreads();
  }
  if (t < SB) bsum[t] = sh[t] - v;  // exclusive
}

__global__ __launch_bounds__(256) void k_pscan3(int* __restrict__ pcount,
                                                const int* __restrict__ bsum) {
  int t = threadIdx.x, b = blockIdx.x;
  int add = bsum[b];
  int base = b * 1024 + t * 4;
  #pragma unroll
  for (int k = 0; k < 4; ++k)
    if (base + k < TOT) pcount[base + k] += add;
}

// staged entry packs src (17 bits) | (dst & 255) << 17
__global__ __launch_bounds__(PTH) void k_pscatter(const int* __restrict__ src,
                                                  const int* __restrict__ dst,
                                                  const int* __restrict__ pcount,
                                                  int* __restrict__ staged) {
  __shared__ int lpos[NBKT];
  int t = threadIdx.x, b = blockIdx.x;
  for (int i = t; i < NBKT; i += PTH) lpos[i] = pcount[i * NBLK + b];
  __syncthreads();
  int base = b * EPB;
  for (int i = t; i < EPB; i += PTH) {
    int s = src[base + i], d = dst[base + i];
    int pos = atomicAdd(&lpos[d >> 8], 1);
    staged[pos] = s | ((d & 255) << 17);
  }
}

__global__ __launch_bounds__(PTH) void k_bucket(const int* __restrict__ staged,
                                                const int* __restrict__ pcount,
                                                int* __restrict__ rowptr,
                                                float* __restrict__ dis,
                                                int* __restrict__ col) {
  __shared__ int lcnt[256];
  __shared__ int lscan[PTH];
  __shared__ int lpos[256];
  int t = threadIdx.x, bkt = blockIdx.x;
  int sbeg = pcount[bkt * NBLK];
  int send = (bkt == NBKT - 1) ? NE : pcount[(bkt + 1) * NBLK];

  if (t < 256) lcnt[t] = 0;
  __syncthreads();
  for (int i = sbeg + t; i < send; i += PTH)
    atomicAdd(&lcnt[(unsigned)staged[i] >> 17], 1);
  __syncthreads();

  int v = (t < 256) ? lcnt[t] : 0;
  lscan[t] = v;
  __syncthreads();
  for (int off = 1; off < PTH; off <<= 1) {
    int x = (t >= off) ? lscan[t - off] : 0;
    __syncthreads();
    lscan[t] += x;
    __syncthreads();
  }
  if (t < 256) {
    int gbase = sbeg + lscan[t] - v;
    int node = bkt * 256 + t;
    if (node < NN) {
      rowptr[node] = gbase;
      dis[node] = rsqrtf((float)(v + 1));  // +1 self-loop
    }
    lpos[t] = gbase;
    if (bkt == NBKT - 1 && t == 0) rowptr[NN] = NE;
  }
  __syncthreads();

  for (int i = sbeg + t; i < send; i += PTH) {
    int e = staged[i];
    col[atomicAdd(&lpos[(unsigned)e >> 17], 1)] = e & 0x1FFFF;
  }
}

__device__ __forceinline__ unsigned bf16rne(float x) {
  unsigned u = __float_as_uint(x);
  return (u + 0x7fffu + ((u >> 16) & 1u)) >> 16;   // round-nearest-even
}

// ---- layer 1 transform: t' = dis * (x @ W), bf16 [NN][64] ----
__global__ __launch_bounds__(256) void k_xform(const float* __restrict__ h,
                                               const float* __restrict__ W,
                                               const float* __restrict__ dis,
                                               unsigned short* __restrict__ ts) {
  __shared__ float hT[64][132];  // [k][row]
  __shared__ float Wl[64][68];   // [k][col]
  const int tid = threadIdx.x;
  const int R0 = blockIdx.x * 128;

  {
    const float4* W4 = (const float4*)W;
    #pragma unroll
    for (int j = 0; j < 4; ++j) {
      int idx = tid + 256 * j;
      float4 v = W4[idx];
      int k = idx >> 4;
      int c = (idx & 15) * 4;
      Wl[k][c + 0] = v.x; Wl[k][c + 1] = v.y;
      Wl[k][c + 2] = v.z; Wl[k][c + 3] = v.w;
    }
  }
  {
    #pragma unroll
    for (int j = 0; j < 8; ++j) {
      int idx = tid + 256 * j;
      int r = idx >> 4;
      int k = (idx & 15) * 4;
      int rg = R0 + r; if (rg > NN - 1) rg = NN - 1;
      float4 v = *(const float4*)(h + (size_t)rg * 64 + k);
      hT[k + 0][r] = v.x; hT[k + 1][r] = v.y;
      hT[k + 2][r] = v.z; hT[k + 3][r] = v.w;
    }
  }
  __syncthreads();

  const int tx = tid & 7;
  const int ty = tid >> 3;
  float acc[4][8];
  #pragma unroll
  for (int i = 0; i < 4; ++i)
    #pragma unroll
    for (int j = 0; j < 8; ++j) acc[i][j] = 0.f;

  #pragma unroll 4
  for (int k = 0; k < 64; ++k) {
    float4 hv = *(const float4*)&hT[k][ty * 4];
    float4 w0 = *(const float4*)&Wl[k][tx * 8];
    float4 w1 = *(const float4*)&Wl[k][tx * 8 + 4];
    float hh[4] = {hv.x, hv.y, hv.z, hv.w};
    float wc[8] = {w0.x, w0.y, w0.z, w0.w, w1.x, w1.y, w1.z, w1.w};
    #pragma unroll
    for (int i = 0; i < 4; ++i)
      #pragma unroll
      for (int j = 0; j < 8; ++j)
        acc[i][j] = fmaf(hh[i], wc[j], acc[i][j]);
  }

  #pragma unroll
  for (int i = 0; i < 4; ++i) {
    int r = R0 + ty * 4 + i;
    if (r < NN) {
      float dr = dis[r];
      uint4 pk;
      pk.x = bf16rne(acc[i][0] * dr) | (bf16rne(acc[i][1] * dr) << 16);
      pk.y = bf16rne(acc[i][2] * dr) | (bf16rne(acc[i][3] * dr) << 16);
      pk.z = bf16rne(acc[i][4] * dr) | (bf16rne(acc[i][5] * dr) << 16);
      pk.w = bf16rne(acc[i][6] * dr) | (bf16rne(acc[i][7] * dr) << 16);
      *(uint4*)(ts + (size_t)r * 64 + tx * 8) = pk;
    }
  }
}

// ---- fused: h' = relu(dis_d*(S_sum t') + b) ; t_next = dis * (h' @ Wn) ----
// Round-18 structure (block = 32 nodes, wave gathers 8). Phase 2 runs on
// f16-packed operands: Wp[kp][col] and hp[row][kp] pack k-pairs, contracted
// with v_dot2_f32_f16 (f32 accum) -> half the LDS reads and FMA count.
// LDS 13.8 KB (was 26.1) -> higher occupancy.
__global__ __launch_bounds__(256) void k_fuse(
    const unsigned short* __restrict__ ts, const int* __restrict__ rowptr,
    const int* __restrict__ col, const float* __restrict__ dis,
    const float* __restrict__ bias, const float* __restrict__ Wn,
    unsigned short* __restrict__ tnext)
{
  __shared__ unsigned Wp[32][72];   // [kpair][col] f16 pairs over k, 9216 B
  __shared__ unsigned hp[32][36];   // [row][kpair] f16 pairs, 4608 B
  const int tid  = threadIdx.x;
  const int lane = tid & 63;
  const int slot = lane >> 4;
  const int fq   = lane & 15;
  const int R0   = blockIdx.x * 32;
  const int wloc = tid >> 6;            // wave in block 0..3
  const int wid  = __builtin_amdgcn_readfirstlane(
                     (int)(blockIdx.x * 4 + wloc));
  const int n0   = wid * 8;

  // stage Wn packed: task = (kp, colquad); 512 tasks, 2 per thread
  {
    const float4* W4 = (const float4*)Wn;
    #pragma unroll
    for (int it = 0; it < 2; ++it) {
      int task = tid + 256 * it;        // 0..511
      int kp = task >> 4;               // k-pair 0..31
      int cq = task & 15;               // col quad 0..15
      float4 a = W4[(2 * kp) * 16 + cq];      // row 2kp, cols cq*4..
      float4 b = W4[(2 * kp + 1) * 16 + cq];  // row 2kp+1
      Wp[kp][cq * 4 + 0] = packf16(a.x, b.x);
      Wp[kp][cq * 4 + 1] = packf16(a.y, b.y);
      Wp[kp][cq * 4 + 2] = packf16(a.z, b.z);
      Wp[kp][cq * 4 + 3] = packf16(a.w, b.w);
    }
  }

  const float4 bv = *(const float4*)(bias + fq * 4);
  const float m_self = (slot == 0) ? 1.f : 0.f;

  i32x16 rp;
  asm volatile("s_load_dwordx16 %0, %1, 0x0\n\ts_waitcnt lgkmcnt(0)"
               : "=s"(rp) : "s"(rowptr + n0));

  float a[8][4];
  #pragma unroll
  for (int i = 0; i < 8; ++i) {
    const uint2 sv = *(const uint2*)(ts + (size_t)(n0 + i) * 64 + fq * 4);
    a[i][0] = m_self * __uint_as_float(sv.x << 16);
    a[i][1] = m_self * __uint_as_float(sv.x & 0xffff0000u);
    a[i][2] = m_self * __uint_as_float(sv.y << 16);
    a[i][3] = m_self * __uint_as_float(sv.y & 0xffff0000u);
  }

  // phase 1a: first 16 edges of each node, straight-line & masked
  #pragma unroll
  for (int i = 0; i < 8; ++i) {
    const int r0 = rp[i], r1 = rp[i + 1];
    #pragma unroll
    for (int s = 0; s < 4; ++s) {
      int e = r0 + s * 4 + slot;
      int c = col[e];
      bool valid = e < r1;
      c = valid ? c : 0;
      float m = valid ? 1.f : 0.f;
      const uint2 gv = *(const uint2*)(ts + (size_t)c * 64 + fq * 4);
      a[i][0] = fmaf(m, __uint_as_float(gv.x << 16),         a[i][0]);
      a[i][1] = fmaf(m, __uint_as_float(gv.x & 0xffff0000u), a[i][1]);
      a[i][2] = fmaf(m, __uint_as_float(gv.y << 16),         a[i][2]);
      a[i][3] = fmaf(m, __uint_as_float(gv.y & 0xffff0000u), a[i][3]);
    }
  }

  // phase 1b: remainders (deg > 16)
  #pragma unroll
  for (int i = 0; i < 8; ++i) {
    const int r1 = rp[i + 1];
    #pragma unroll 1
    for (int e0 = rp[i] + 16; e0 < r1; e0 += 8) {
      #pragma unroll
      for (int s = 0; s < 2; ++s) {
        int e = e0 + s * 4 + slot;
        int c = col[e];
        bool valid = e < r1;
        c = valid ? c : 0;
        float m = valid ? 1.f : 0.f;
        const uint2 gv = *(const uint2*)(ts + (size_t)c * 64 + fq * 4);
        a[i][0] = fmaf(m, __uint_as_float(gv.x << 16),         a[i][0]);
        a[i][1] = fmaf(m, __uint_as_float(gv.x & 0xffff0000u), a[i][1]);
        a[i][2] = fmaf(m, __uint_as_float(gv.y << 16),         a[i][2]);
        a[i][3] = fmaf(m, __uint_as_float(gv.y & 0xffff0000u), a[i][3]);
      }
    }
  }

  // reduce across slots; h' = relu(dn*s + b) -> hp packed f16 pairs over k
  #pragma unroll
  for (int i = 0; i < 8; ++i) {
    const int node = n0 + i;
    const float dn = dis[node];
    float s0 = a[i][0], s1 = a[i][1], s2 = a[i][2], s3 = a[i][3];
    s0 += __shfl_xor(s0, 16); s1 += __shfl_xor(s1, 16);
    s2 += __shfl_xor(s2, 16); s3 += __shfl_xor(s3, 16);
    s0 += __shfl_xor(s0, 32); s1 += __shfl_xor(s1, 32);
    s2 += __shfl_xor(s2, 32); s3 += __shfl_xor(s3, 32);
    float o0 = fmaxf(fmaf(dn, s0, bv.x), 0.f);
    float o1 = fmaxf(fmaf(dn, s1, bv.y), 0.f);
    float o2 = fmaxf(fmaf(dn, s2, bv.z), 0.f);
    float o3 = fmaxf(fmaf(dn, s3, bv.w), 0.f);
    if (lane < 16) {
      // cols fq*4..fq*4+3 == k-pairs 2fq, 2fq+1
      uint2 pk = make_uint2(packf16(o0, o1), packf16(o2, o3));
      *(uint2*)&hp[wloc * 8 + i][fq * 2] = pk;
    }
  }
  __syncthreads();

  // phase 2: t_next = dis * (h' @ Wn) via dot2; ty=row, tx=col-group
  const int tx = tid & 7;     // col group (8 cols)
  const int ty = tid >> 3;    // row 0..31
  float acc[8];
  #pragma unroll
  for (int j = 0; j < 8; ++j) acc[j] = 0.f;
  #pragma unroll 4
  for (int kp = 0; kp < 32; ++kp) {
    unsigned hv = hp[ty][kp];
    uint4 w0 = *(const uint4*)&Wp[kp][tx * 8];
    uint4 w1 = *(const uint4*)&Wp[kp][tx * 8 + 4];
    acc[0] = dot2(hv, w0.x, acc[0]); acc[1] = dot2(hv, w0.y, acc[1]);
    acc[2] = dot2(hv, w0.z, acc[2]); acc[3] = dot2(hv, w0.w, acc[3]);
    acc[4] = dot2(hv, w1.x, acc[4]); acc[5] = dot2(hv, w1.y, acc[5]);
    acc[6] = dot2(hv, w1.z, acc[6]); acc[7] = dot2(hv, w1.w, acc[7]);
  }
  {
    int r = R0 + ty;
    float dr = dis[r];
    uint4 pk;
    pk.x = bf16rne(acc[0] * dr) | (bf16rne(acc[1] * dr) << 16);
    pk.y = bf16rne(acc[2] * dr) | (bf16rne(acc[3] * dr) << 16);
    pk.z = bf16rne(acc[4] * dr) | (bf16rne(acc[5] * dr) << 16);
    pk.w = bf16rne(acc[6] * dr) | (bf16rne(acc[7] * dr) << 16);
    *(uint4*)(tnext + (size_t)r * 64 + tx * 8) = pk;
  }
}

// ---- final layer: out = dis_d*(S_sum t') + b  (fp32, no relu) ----
__global__ __launch_bounds__(256) void k_agg(
    const unsigned short* __restrict__ ts, const int* __restrict__ rowptr,
    const int* __restrict__ col, const float* __restrict__ dis,
    const float* __restrict__ bias, float* __restrict__ out)
{
  const int lane = threadIdx.x & 63;
  const int slot = lane >> 4;
  const int fq   = lane & 15;
  const int wid  = __builtin_amdgcn_readfirstlane(
                     (int)((blockIdx.x * blockDim.x + threadIdx.x) >> 6));
  const int n0   = wid * 8;
  if (n0 >= NN) return;

  const float4 bv = *(const float4*)(bias + fq * 4);
  const float m_self = (slot == 0) ? 1.f : 0.f;

  i32x16 rp;
  asm volatile("s_load_dwordx16 %0, %1, 0x0\n\ts_waitcnt lgkmcnt(0)"
               : "=s"(rp) : "s"(rowptr + n0));

  float a[8][4];
  #pragma unroll
  for (int i = 0; i < 8; ++i) {
    const uint2 sv = *(const uint2*)(ts + (size_t)(n0 + i) * 64 + fq * 4);
    a[i][0] = m_self * __uint_as_float(sv.x << 16);
    a[i][1] = m_self * __uint_as_float(sv.x & 0xffff0000u);
    a[i][2] = m_self * __uint_as_float(sv.y << 16);
    a[i][3] = m_self * __uint_as_float(sv.y & 0xffff0000u);
  }

  #pragma unroll
  for (int i = 0; i < 8; ++i) {
    const int r0 = rp[i], r1 = rp[i + 1];
    #pragma unroll
    for (int s = 0; s < 4; ++s) {
      int e = r0 + s * 4 + slot;
      int c = col[e];
      bool valid = e < r1;
      c = valid ? c : 0;
      float m = valid ? 1.f : 0.f;
      const uint2 gv = *(const uint2*)(ts + (size_t)c * 64 + fq * 4);
      a[i][0] = fmaf(m, __uint_as_float(gv.x << 16),         a[i][0]);
      a[i][1] = fmaf(m, __uint_as_float(gv.x & 0xffff0000u), a[i][1]);
      a[i][2] = fmaf(m, __uint_as_float(gv.y << 16),         a[i][2]);
      a[i][3] = fmaf(m, __uint_as_float(gv.y & 0xffff0000u), a[i][3]);
    }
  }

  #pragma unroll
  for (int i = 0; i < 8; ++i) {
    const int r1 = rp[i + 1];
    #pragma unroll 1
    for (int e0 = rp[i] + 16; e0 < r1; e0 += 8) {
      #pragma unroll
      for (int s = 0; s < 2; ++s) {
        int e = e0 + s * 4 + slot;
        int c = col[e];
        bool valid = e < r1;
        c = valid ? c : 0;
        float m = valid ? 1.f : 0.f;
        const uint2 gv = *(const uint2*)(ts + (size_t)c * 64 + fq * 4);
        a[i][0] = fmaf(m, __uint_as_float(gv.x << 16),         a[i][0]);
        a[i][1] = fmaf(m, __uint_as_float(gv.x & 0xffff0000u), a[i][1]);
        a[i][2] = fmaf(m, __uint_as_float(gv.y << 16),         a[i][2]);
        a[i][3] = fmaf(m, __uint_as_float(gv.y & 0xffff0000u), a[i][3]);
      }
    }
  }

  #pragma unroll
  for (int i = 0; i < 8; ++i) {
    const int node = n0 + i;
    const float dn = dis[node];
    float s0 = a[i][0], s1 = a[i][1], s2 = a[i][2], s3 = a[i][3];
    s0 += __shfl_xor(s0, 16); s1 += __shfl_xor(s1, 16);
    s2 += __shfl_xor(s2, 16); s3 += __shfl_xor(s3, 16);
    s0 += __shfl_xor(s0, 32); s1 += __shfl_xor(s1, 32);
    s2 += __shfl_xor(s2, 32); s3 += __shfl_xor(s3, 32);
    float4 o;
    o.x = fmaf(dn, s0, bv.x); o.y = fmaf(dn, s1, bv.y);
    o.z = fmaf(dn, s2, bv.z); o.w = fmaf(dn, s3, bv.w);
    if (lane < 16)
      *(float4*)(out + (size_t)node * 64 + fq * 4) = o;
  }
}

extern "C" void kernel_launch(void* const* d_in, const int* in_sizes, int n_in,
                              void* d_out, int out_size, void* d_ws, size_t ws_size,
                              hipStream_t stream) {
  const float* x  = (const float*)d_in[0];
  const int*   ei = (const int*)d_in[1];
  const float* W1 = (const float*)d_in[2];
  const float* b1 = (const float*)d_in[3];
  const float* W2 = (const float*)d_in[4];
  const float* b2 = (const float*)d_in[5];
  const float* W3 = (const float*)d_in[6];
  const float* b3 = (const float*)d_in[7];
  float* out = (float*)d_out;

  const int* src = ei;        // edge_index[0]
  const int* dst = ei + NE;   // edge_index[1]

  char* ws = (char*)d_ws;
  size_t off = 0;
  auto alloc = [&](size_t bytes) {
    void* p = ws + off;
    off = (off + bytes + 255) & ~(size_t)255;
    return p;
  };
  int*   pcount = (int*)alloc((size_t)TOT * 4);
  int*   bsum   = (int*)alloc((size_t)SB * 4);
  int*   rowptr = (int*)alloc((size_t)(NN + 1 + 16) * 4); // +16: s_load overrun pad
  float* dis    = (float*)alloc((size_t)NN * 4);
  int*   staged = (int*)alloc((size_t)NE * 4);            // packed src|dst8
  int*   col    = (int*)alloc((size_t)(NE + 64) * 4);     // +64: load overrun pad
  unsigned short* tb1 =
      (unsigned short*)alloc((size_t)NN * 64 * 2);        // bf16 [NN][64]
  unsigned short* tb2 =
      (unsigned short*)alloc((size_t)NN * 64 * 2);        // bf16 [NN][64]
  (void)ws_size; (void)in_sizes; (void)n_in; (void)out_size;

  k_pcount  <<<NBLK, PTH, 0, stream>>>(dst, pcount);
  k_pscan1  <<<SB, 256, 0, stream>>>(pcount, bsum);
  k_pscan2  <<<1, 128, 0, stream>>>(bsum);
  k_pscan3  <<<SB, 256, 0, stream>>>(pcount, bsum);
  k_pscatter<<<NBLK, PTH, 0, stream>>>(src, dst, pcount, staged);
  k_bucket  <<<NBKT, PTH, 0, stream>>>(staged, pcount, rowptr, dis, col);

  const int XF_BLOCKS = (NN + 127) / 128;   // 782
  const int FB        = NN / 32;            // 3125, exact

  k_xform<<<XF_BLOCKS, 256, 0, stream>>>(x, W1, dis, tb1);
  k_fuse <<<FB, 256, 0, stream>>>(tb1, rowptr, col, dis, b1, W2, tb2);
  k_fuse <<<FB, 256, 0, stream>>>(tb2, rowptr, col, dis, b2, W3, tb1);
  k_agg  <<<FB, 256, 0, stream>>>(tb1, rowptr, col, dis, b3, out);
}

// Round 21
// 165.896 us; speedup vs baseline: 1.1759x; 1.0278x over previous
//
#include <hip/hip_runtime.h>

#define NN 100000
#define NE 1600000

typedef __attribute__((ext_vector_type(16))) int i32x16;
typedef _Float16 f16x2 __attribute__((ext_vector_type(2)));

// f32 += dot(packed f16 pair, packed f16 pair)
__device__ __forceinline__ float dot2(unsigned h, unsigned w, float c) {
  f16x2 a = __builtin_bit_cast(f16x2, h);
  f16x2 b = __builtin_bit_cast(f16x2, w);
#if __has_builtin(__builtin_amdgcn_fdot2)
  return __builtin_amdgcn_fdot2(a, b, c, false);
#else
  return fmaf((float)a.x, (float)b.x, fmaf((float)a.y, (float)b.y, c));
#endif
}

__device__ __forceinline__ unsigned packf16(float lo, float hi) {
  f16x2 v = {(_Float16)lo, (_Float16)hi};
  return __builtin_bit_cast(unsigned, v);
}

// ---- bucketed CSR build ----
// bucket = dst >> 8  (256 nodes per bucket)
#define NBKT 391                 // ceil(100000 / 256)
#define NBLK 256                 // partition blocks
#define EPB  (NE / NBLK)         // 6250 edges per partition block
#define PTH  512                 // threads in partition/bucket kernels
#define TOT  (NBKT * NBLK)       // 100096 pcount entries
#define SB   ((TOT + 1023) / 1024)  // 98 scan blocks

__global__ __launch_bounds__(PTH) void k_pcount(const int* __restrict__ dst,
                                                int* __restrict__ pcount) {
  __shared__ int lcnt[NBKT];
  int t = threadIdx.x, b = blockIdx.x;
  for (int i = t; i < NBKT; i += PTH) lcnt[i] = 0;
  __syncthreads();
  int base = b * EPB;
  for (int i = t; i < EPB; i += PTH)
    atomicAdd(&lcnt[dst[base + i] >> 8], 1);
  __syncthreads();
  for (int i = t; i < NBKT; i += PTH)
    pcount[i * NBLK + b] = lcnt[i];   // bucket-major layout
}

// hierarchical exclusive scan of pcount[TOT]
__global__ __launch_bounds__(256) void k_pscan1(int* __restrict__ pcount,
                                                int* __restrict__ bsum) {
  __shared__ int sh[256];
  int t = threadIdx.x, b = blockIdx.x;
  int base = b * 1024 + t * 4;
  int v0 = (base + 0 < TOT) ? pcount[base + 0] : 0;
  int v1 = (base + 1 < TOT) ? pcount[base + 1] : 0;
  int v2 = (base + 2 < TOT) ? pcount[base + 2] : 0;
  int v3 = (base + 3 < TOT) ? pcount[base + 3] : 0;
  int s = v0 + v1 + v2 + v3;
  sh[t] = s;
  __syncthreads();
  for (int off = 1; off < 256; off <<= 1) {
    int x = (t >= off) ? sh[t - off] : 0;
    __syncthreads();
    sh[t] += x;
    __syncthreads();
  }
  int ex = sh[t] - s;
  if (t == 255) bsum[b] = sh[255];
  if (base + 0 < TOT) pcount[base + 0] = ex; ex += v0;
  if (base + 1 < TOT) pcount[base + 1] = ex; ex += v1;
  if (base + 2 < TOT) pcount[base + 2] = ex; ex += v2;
  if (base + 3 < TOT) pcount[base + 3] = ex;
}

__global__ __launch_bounds__(128) void k_pscan2(int* __restrict__ bsum) {
  __shared__ int sh[128];
  int t = threadIdx.x;
  int v = (t < SB) ? bsum[t] : 0;
  sh[t] = v;
  __syncthreads();
  for (int off = 1; off < 128; off <<= 1) {
    int x = (t >= off) ? sh[t - off] : 0;
    __syncthreads();
    sh[t] += x;
    __syncthreads();
  }
  if (t < SB) bsum[t] = sh[t] - v;  // exclusive
}

__global__ __launch_bounds__(256) void k_pscan3(int* __restrict__ pcount,
                                                const int* __restrict__ bsum) {
  int t = threadIdx.x, b = blockIdx.x;
  int add = bsum[b];
  int base = b * 1024 + t * 4;
  #pragma unroll
  for (int k = 0; k < 4; ++k)
    if (base + k < TOT) pcount[base + k] += add;
}

// staged entry packs src (17 bits) | (dst & 255) << 17
__global__ __launch_bounds__(PTH) void k_pscatter(const int* __restrict__ src,
                                                  const int* __restrict__ dst,
                                                  const int* __restrict__ pcount,
                                                  int* __restrict__ staged) {
  __shared__ int lpos[NBKT];
  int t = threadIdx.x, b = blockIdx.x;
  for (int i = t; i < NBKT; i += PTH) lpos[i] = pcount[i * NBLK + b];
  __syncthreads();
  int base = b * EPB;
  for (int i = t; i < EPB; i += PTH) {
    int s = src[base + i], d = dst[base + i];
    int pos = atomicAdd(&lpos[d >> 8], 1);
    staged[pos] = s | ((d & 255) << 17);
  }
}

__global__ __launch_bounds__(PTH) void k_bucket(const int* __restrict__ staged,
                                                const int* __restrict__ pcount,
                                                int* __restrict__ rowptr,
                                                float* __restrict__ dis,
                                                int* __restrict__ col) {
  __shared__ int lcnt[256];
  __shared__ int lscan[PTH];
  __shared__ int lpos[256];
  int t = threadIdx.x, bkt = blockIdx.x;
  int sbeg = pcount[bkt * NBLK];
  int send = (bkt == NBKT - 1) ? NE : pcount[(bkt + 1) * NBLK];

  if (t < 256) lcnt[t] = 0;
  __syncthreads();
  for (int i = sbeg + t; i < send; i += PTH)
    atomicAdd(&lcnt[(unsigned)staged[i] >> 17], 1);
  __syncthreads();

  int v = (t < 256) ? lcnt[t] : 0;
  lscan[t] = v;
  __syncthreads();
  for (int off = 1; off < PTH; off <<= 1) {
    int x = (t >= off) ? lscan[t - off] : 0;
    __syncthreads();
    lscan[t] += x;
    __syncthreads();
  }
  if (t < 256) {
    int gbase = sbeg + lscan[t] - v;
    int node = bkt * 256 + t;
    if (node < NN) {
      rowptr[node] = gbase;
      dis[node] = rsqrtf((float)(v + 1));  // +1 self-loop
    }
    lpos[t] = gbase;
    if (bkt == NBKT - 1 && t == 0) rowptr[NN] = NE;
  }
  __syncthreads();

  for (int i = sbeg + t; i < send; i += PTH) {
    int e = staged[i];
    col[atomicAdd(&lpos[(unsigned)e >> 17], 1)] = e & 0x1FFFF;
  }
}

__device__ __forceinline__ unsigned bf16rne(float x) {
  unsigned u = __float_as_uint(x);
  return (u + 0x7fffu + ((u >> 16) & 1u)) >> 16;   // round-nearest-even
}

// ---- layer 1 transform: t' = dis * (x @ W), bf16 [NN][64] ----
// f16-dot2 version: x packed as k-pairs transposed hTp[kp][row] (16B-aligned
// rows -> conflict-free b128 reads of 4 rows), W packed Wp[kp][col].
// Per kp-iter: 3x ds_read_b128 + 32 dot2 -> half the LDS reads and VALU ops.
__global__ __launch_bounds__(256) void k_xform(const float* __restrict__ h,
                                               const float* __restrict__ W,
                                               const float* __restrict__ dis,
                                               unsigned short* __restrict__ ts) {
  __shared__ unsigned hTp[32][132];  // [kpair][row], stride 528 B (16B-mult)
  __shared__ unsigned Wp[32][72];    // [kpair][col]
  const int tid = threadIdx.x;
  const int R0 = blockIdx.x * 128;

  // stage W packed: 512 tasks (kp, colquad), 2 per thread
  {
    const float4* W4 = (const float4*)W;
    #pragma unroll
    for (int it = 0; it < 2; ++it) {
      int task = tid + 256 * it;
      int kp = task >> 4;
      int cq = task & 15;
      float4 a = W4[(2 * kp) * 16 + cq];
      float4 b = W4[(2 * kp + 1) * 16 + cq];
      Wp[kp][cq * 4 + 0] = packf16(a.x, b.x);
      Wp[kp][cq * 4 + 1] = packf16(a.y, b.y);
      Wp[kp][cq * 4 + 2] = packf16(a.z, b.z);
      Wp[kp][cq * 4 + 3] = packf16(a.w, b.w);
    }
  }
  // stage x tile packed-transposed: 2048 float4 loads -> 2 uint writes each
  {
    #pragma unroll
    for (int j = 0; j < 8; ++j) {
      int idx = tid + 256 * j;
      int r = idx >> 4;                 // row 0..127
      int kp = (idx & 15) * 2;          // k-pairs kp, kp+1
      int rg = R0 + r; if (rg > NN - 1) rg = NN - 1;
      float4 v = *(const float4*)(h + (size_t)rg * 64 + kp * 2);
      hTp[kp][r]     = packf16(v.x, v.y);
      hTp[kp + 1][r] = packf16(v.z, v.w);
    }
  }
  __syncthreads();

  const int tx = tid & 7;    // cols tx*8..tx*8+7
  const int ty = tid >> 3;   // rows ty*4..ty*4+3
  float acc[4][8];
  #pragma unroll
  for (int i = 0; i < 4; ++i)
    #pragma unroll
    for (int j = 0; j < 8; ++j) acc[i][j] = 0.f;

  #pragma unroll 4
  for (int kp = 0; kp < 32; ++kp) {
    uint4 hv = *(const uint4*)&hTp[kp][ty * 4];   // 4 rows, this k-pair
    uint4 w0 = *(const uint4*)&Wp[kp][tx * 8];
    uint4 w1 = *(const uint4*)&Wp[kp][tx * 8 + 4];
    unsigned hh[4] = {hv.x, hv.y, hv.z, hv.w};
    unsigned wc[8] = {w0.x, w0.y, w0.z, w0.w, w1.x, w1.y, w1.z, w1.w};
    #pragma unroll
    for (int i = 0; i < 4; ++i)
      #pragma unroll
      for (int j = 0; j < 8; ++j)
        acc[i][j] = dot2(hh[i], wc[j], acc[i][j]);
  }

  #pragma unroll
  for (int i = 0; i < 4; ++i) {
    int r = R0 + ty * 4 + i;
    if (r < NN) {
      float dr = dis[r];
      uint4 pk;
      pk.x = bf16rne(acc[i][0] * dr) | (bf16rne(acc[i][1] * dr) << 16);
      pk.y = bf16rne(acc[i][2] * dr) | (bf16rne(acc[i][3] * dr) << 16);
      pk.z = bf16rne(acc[i][4] * dr) | (bf16rne(acc[i][5] * dr) << 16);
      pk.w = bf16rne(acc[i][6] * dr) | (bf16rne(acc[i][7] * dr) << 16);
      *(uint4*)(ts + (size_t)r * 64 + tx * 8) = pk;
    }
  }
}

// ---- fused: h' = relu(dis_d*(S_sum t') + b) ; t_next = dis * (h' @ Wn) ----
// Barrier moved to right after W staging: each wave's phase 2 reads ONLY
// its own hp rows (rows 8w..8w+7), so gather -> GEMM flows without a block
// barrier -- early waves' GEMM overlaps late waves' gather latency.
__global__ __launch_bounds__(256) void k_fuse(
    const unsigned short* __restrict__ ts, const int* __restrict__ rowptr,
    const int* __restrict__ col, const float* __restrict__ dis,
    const float* __restrict__ bias, const float* __restrict__ Wn,
    unsigned short* __restrict__ tnext)
{
  __shared__ unsigned Wp[32][72];   // [kpair][col] f16 pairs over k
  __shared__ unsigned hp[32][36];   // [row][kpair] f16 pairs
  const int tid  = threadIdx.x;
  const int lane = tid & 63;
  const int slot = lane >> 4;
  const int fq   = lane & 15;
  const int R0   = blockIdx.x * 32;
  const int wloc = tid >> 6;            // wave in block 0..3
  const int wid  = __builtin_amdgcn_readfirstlane(
                     (int)(blockIdx.x * 4 + wloc));
  const int n0   = wid * 8;

  // stage Wn packed: task = (kp, colquad); 512 tasks, 2 per thread
  {
    const float4* W4 = (const float4*)Wn;
    #pragma unroll
    for (int it = 0; it < 2; ++it) {
      int task = tid + 256 * it;        // 0..511
      int kp = task >> 4;               // k-pair 0..31
      int cq = task & 15;               // col quad 0..15
      float4 a = W4[(2 * kp) * 16 + cq];      // row 2kp, cols cq*4..
      float4 b = W4[(2 * kp + 1) * 16 + cq];  // row 2kp+1
      Wp[kp][cq * 4 + 0] = packf16(a.x, b.x);
      Wp[kp][cq * 4 + 1] = packf16(a.y, b.y);
      Wp[kp][cq * 4 + 2] = packf16(a.z, b.z);
      Wp[kp][cq * 4 + 3] = packf16(a.w, b.w);
    }
  }
  __syncthreads();   // Wp ready; the ONLY block barrier

  const float4 bv = *(const float4*)(bias + fq * 4);
  const float m_self = (slot == 0) ? 1.f : 0.f;

  i32x16 rp;
  asm volatile("s_load_dwordx16 %0, %1, 0x0\n\ts_waitcnt lgkmcnt(0)"
               : "=s"(rp) : "s"(rowptr + n0));

  float a[8][4];
  #pragma unroll
  for (int i = 0; i < 8; ++i) {
    const uint2 sv = *(const uint2*)(ts + (size_t)(n0 + i) * 64 + fq * 4);
    a[i][0] = m_self * __uint_as_float(sv.x << 16);
    a[i][1] = m_self * __uint_as_float(sv.x & 0xffff0000u);
    a[i][2] = m_self * __uint_as_float(sv.y << 16);
    a[i][3] = m_self * __uint_as_float(sv.y & 0xffff0000u);
  }

  // phase 1a: first 16 edges of each node, straight-line & masked
  #pragma unroll
  for (int i = 0; i < 8; ++i) {
    const int r0 = rp[i], r1 = rp[i + 1];
    #pragma unroll
    for (int s = 0; s < 4; ++s) {
      int e = r0 + s * 4 + slot;
      int c = col[e];
      bool valid = e < r1;
      c = valid ? c : 0;
      float m = valid ? 1.f : 0.f;
      const uint2 gv = *(const uint2*)(ts + (size_t)c * 64 + fq * 4);
      a[i][0] = fmaf(m, __uint_as_float(gv.x << 16),         a[i][0]);
      a[i][1] = fmaf(m, __uint_as_float(gv.x & 0xffff0000u), a[i][1]);
      a[i][2] = fmaf(m, __uint_as_float(gv.y << 16),         a[i][2]);
      a[i][3] = fmaf(m, __uint_as_float(gv.y & 0xffff0000u), a[i][3]);
    }
  }

  // phase 1b: remainders (deg > 16)
  #pragma unroll
  for (int i = 0; i < 8; ++i) {
    const int r1 = rp[i + 1];
    #pragma unroll 1
    for (int e0 = rp[i] + 16; e0 < r1; e0 += 8) {
      #pragma unroll
      for (int s = 0; s < 2; ++s) {
        int e = e0 + s * 4 + slot;
        int c = col[e];
        bool valid = e < r1;
        c = valid ? c : 0;
        float m = valid ? 1.f : 0.f;
        const uint2 gv = *(const uint2*)(ts + (size_t)c * 64 + fq * 4);
        a[i][0] = fmaf(m, __uint_as_float(gv.x << 16),         a[i][0]);
        a[i][1] = fmaf(m, __uint_as_float(gv.x & 0xffff0000u), a[i][1]);
        a[i][2] = fmaf(m, __uint_as_float(gv.y << 16),         a[i][2]);
        a[i][3] = fmaf(m, __uint_as_float(gv.y & 0xffff0000u), a[i][3]);
      }
    }
  }

  // reduce across slots; h' = relu(dn*s + b) -> hp (this wave's rows only)
  #pragma unroll
  for (int i = 0; i < 8; ++i) {
    const int node = n0 + i;
    const float dn = dis[node];
    float s0 = a[i][0], s1 = a[i][1], s2 = a[i][2], s3 = a[i][3];
    s0 += __shfl_xor(s0, 16); s1 += __shfl_xor(s1, 16);
    s2 += __shfl_xor(s2, 16); s3 += __shfl_xor(s3, 16);
    s0 += __shfl_xor(s0, 32); s1 += __shfl_xor(s1, 32);
    s2 += __shfl_xor(s2, 32); s3 += __shfl_xor(s3, 32);
    float o0 = fmaxf(fmaf(dn, s0, bv.x), 0.f);
    float o1 = fmaxf(fmaf(dn, s1, bv.y), 0.f);
    float o2 = fmaxf(fmaf(dn, s2, bv.z), 0.f);
    float o3 = fmaxf(fmaf(dn, s3, bv.w), 0.f);
    if (lane < 16) {
      uint2 pk = make_uint2(packf16(o0, o1), packf16(o2, o3));
      *(uint2*)&hp[wloc * 8 + i][fq * 2] = pk;
    }
  }
  // NO barrier: wave w's phase 2 reads rows 8w..8w+7, written by itself;
  // hardware lgkmcnt orders the same-wave LDS RAW.

  // phase 2: t_next = dis * (h' @ Wn) via dot2; ty=row, tx=col-group
  const int tx = tid & 7;     // col group (8 cols)
  const int ty = tid >> 3;    // row 0..31 (== wloc*8 .. wloc*8+7 per wave)
  float acc[8];
  #pragma unroll
  for (int j = 0; j < 8; ++j) acc[j] = 0.f;
  #pragma unroll 4
  for (int kp = 0; kp < 32; ++kp) {
    unsigned hv = hp[ty][kp];
    uint4 w0 = *(const uint4*)&Wp[kp][tx * 8];
    uint4 w1 = *(const uint4*)&Wp[kp][tx * 8 + 4];
    acc[0] = dot2(hv, w0.x, acc[0]); acc[1] = dot2(hv, w0.y, acc[1]);
    acc[2] = dot2(hv, w0.z, acc[2]); acc[3] = dot2(hv, w0.w, acc[3]);
    acc[4] = dot2(hv, w1.x, acc[4]); acc[5] = dot2(hv, w1.y, acc[5]);
    acc[6] = dot2(hv, w1.z, acc[6]); acc[7] = dot2(hv, w1.w, acc[7]);
  }
  {
    int r = R0 + ty;
    float dr = dis[r];
    uint4 pk;
    pk.x = bf16rne(acc[0] * dr) | (bf16rne(acc[1] * dr) << 16);
    pk.y = bf16rne(acc[2] * dr) | (bf16rne(acc[3] * dr) << 16);
    pk.z = bf16rne(acc[4] * dr) | (bf16rne(acc[5] * dr) << 16);
    pk.w = bf16rne(acc[6] * dr) | (bf16rne(acc[7] * dr) << 16);
    *(uint4*)(tnext + (size_t)r * 64 + tx * 8) = pk;
  }
}

// ---- final layer: out = dis_d*(S_sum t') + b  (fp32, no relu) ----
__global__ __launch_bounds__(256) void k_agg(
    const unsigned short* __restrict__ ts, const int* __restrict__ rowptr,
    const int* __restrict__ col, const float* __restrict__ dis,
    const float* __restrict__ bias, float* __restrict__ out)
{
  const int lane = threadIdx.x & 63;
  const int slot = lane >> 4;
  const int fq   = lane & 15;
  const int wid  = __builtin_amdgcn_readfirstlane(
                     (int)((blockIdx.x * blockDim.x + threadIdx.x) >> 6));
  const int n0   = wid * 8;
  if (n0 >= NN) return;

  const float4 bv = *(const float4*)(bias + fq * 4);
  const float m_self = (slot == 0) ? 1.f : 0.f;

  i32x16 rp;
  asm volatile("s_load_dwordx16 %0, %1, 0x0\n\ts_waitcnt lgkmcnt(0)"
               : "=s"(rp) : "s"(rowptr + n0));

  float a[8][4];
  #pragma unroll
  for (int i = 0; i < 8; ++i) {
    const uint2 sv = *(const uint2*)(ts + (size_t)(n0 + i) * 64 + fq * 4);
    a[i][0] = m_self * __uint_as_float(sv.x << 16);
    a[i][1] = m_self * __uint_as_float(sv.x & 0xffff0000u);
    a[i][2] = m_self * __uint_as_float(sv.y << 16);
    a[i][3] = m_self * __uint_as_float(sv.y & 0xffff0000u);
  }

  #pragma unroll
  for (int i = 0; i < 8; ++i) {
    const int r0 = rp[i], r1 = rp[i + 1];
    #pragma unroll
    for (int s = 0; s < 4; ++s) {
      int e = r0 + s * 4 + slot;
      int c = col[e];
      bool valid = e < r1;
      c = valid ? c : 0;
      float m = valid ? 1.f : 0.f;
      const uint2 gv = *(const uint2*)(ts + (size_t)c * 64 + fq * 4);
      a[i][0] = fmaf(m, __uint_as_float(gv.x << 16),         a[i][0]);
      a[i][1] = fmaf(m, __uint_as_float(gv.x & 0xffff0000u), a[i][1]);
      a[i][2] = fmaf(m, __uint_as_float(gv.y << 16),         a[i][2]);
      a[i][3] = fmaf(m, __uint_as_float(gv.y & 0xffff0000u), a[i][3]);
    }
  }

  #pragma unroll
  for (int i = 0; i < 8; ++i) {
    const int r1 = rp[i + 1];
    #pragma unroll 1
    for (int e0 = rp[i] + 16; e0 < r1; e0 += 8) {
      #pragma unroll
      for (int s = 0; s < 2; ++s) {
        int e = e0 + s * 4 + slot;
        int c = col[e];
        bool valid = e < r1;
        c = valid ? c : 0;
        float m = valid ? 1.f : 0.f;
        const uint2 gv = *(const uint2*)(ts + (size_t)c * 64 + fq * 4);
        a[i][0] = fmaf(m, __uint_as_float(gv.x << 16),         a[i][0]);
        a[i][1] = fmaf(m, __uint_as_float(gv.x & 0xffff0000u), a[i][1]);
        a[i][2] = fmaf(m, __uint_as_float(gv.y << 16),         a[i][2]);
        a[i][3] = fmaf(m, __uint_as_float(gv.y & 0xffff0000u), a[i][3]);
      }
    }
  }

  #pragma unroll
  for (int i = 0; i < 8; ++i) {
    const int node = n0 + i;
    const float dn = dis[node];
    float s0 = a[i][0], s1 = a[i][1], s2 = a[i][2], s3 = a[i][3];
    s0 += __shfl_xor(s0, 16); s1 += __shfl_xor(s1, 16);
    s2 += __shfl_xor(s2, 16); s3 += __shfl_xor(s3, 16);
    s0 += __shfl_xor(s0, 32); s1 += __shfl_xor(s1, 32);
    s2 += __shfl_xor(s2, 32); s3 += __shfl_xor(s3, 32);
    float4 o;
    o.x = fmaf(dn, s0, bv.x); o.y = fmaf(dn, s1, bv.y);
    o.z = fmaf(dn, s2, bv.z); o.w = fmaf(dn, s3, bv.w);
    if (lane < 16)
      *(float4*)(out + (size_t)node * 64 + fq * 4) = o;
  }
}

extern "C" void kernel_launch(void* const* d_in, const int* in_sizes, int n_in,
                              void* d_out, int out_size, void* d_ws, size_t ws_size,
                              hipStream_t stream) {
  const float* x  = (const float*)d_in[0];
  const int*   ei = (const int*)d_in[1];
  const float* W1 = (const float*)d_in[2];
  const float* b1 = (const float*)d_in[3];
  const float* W2 = (const float*)d_in[4];
  const float* b2 = (const float*)d_in[5];
  const float* W3 = (const float*)d_in[6];
  const float* b3 = (const float*)d_in[7];
  float* out = (float*)d_out;

  const int* src = ei;        // edge_index[0]
  const int* dst = ei + NE;   // edge_index[1]

  char* ws = (char*)d_ws;
  size_t off = 0;
  auto alloc = [&](size_t bytes) {
    void* p = ws + off;
    off = (off + bytes + 255) & ~(size_t)255;
    return p;
  };
  int*   pcount = (int*)alloc((size_t)TOT * 4);
  int*   bsum   = (int*)alloc((size_t)SB * 4);
  int*   rowptr = (int*)alloc((size_t)(NN + 1 + 16) * 4); // +16: s_load overrun pad
  float* dis    = (float*)alloc((size_t)NN * 4);
  int*   staged = (int*)alloc((size_t)NE * 4);            // packed src|dst8
  int*   col    = (int*)alloc((size_t)(NE + 64) * 4);     // +64: load overrun pad
  unsigned short* tb1 =
      (unsigned short*)alloc((size_t)NN * 64 * 2);        // bf16 [NN][64]
  unsigned short* tb2 =
      (unsigned short*)alloc((size_t)NN * 64 * 2);        // bf16 [NN][64]
  (void)ws_size; (void)in_sizes; (void)n_in; (void)out_size;

  k_pcount  <<<NBLK, PTH, 0, stream>>>(dst, pcount);
  k_pscan1  <<<SB, 256, 0, stream>>>(pcount, bsum);
  k_pscan2  <<<1, 128, 0, stream>>>(bsum);
  k_pscan3  <<<SB, 256, 0, stream>>>(pcount, bsum);
  k_pscatter<<<NBLK, PTH, 0, stream>>>(src, dst, pcount, staged);
  k_bucket  <<<NBKT, PTH, 0, stream>>>(staged, pcount, rowptr, dis, col);

  const int XF_BLOCKS = (NN + 127) / 128;   // 782
  const int FB        = NN / 32;            // 3125, exact

  k_xform<<<XF_BLOCKS, 256, 0, stream>>>(x, W1, dis, tb1);
  k_fuse <<<FB, 256, 0, stream>>>(tb1, rowptr, col, dis, b1, W2, tb2);
  k_fuse <<<FB, 256, 0, stream>>>(tb2, rowptr, col, dis, b2, W3, tb1);
  k_agg  <<<FB, 256, 0, stream>>>(tb1, rowptr, col, dis, b3, out);
}

// Round 22
// 165.339 us; speedup vs baseline: 1.1799x; 1.0034x over previous
//
#include <hip/hip_runtime.h>

#define NN 100000
#define NE 1600000

typedef __attribute__((ext_vector_type(16))) int i32x16;
typedef _Float16 f16x2 __attribute__((ext_vector_type(2)));

// f32 += dot(packed f16 pair, packed f16 pair)
__device__ __forceinline__ float dot2(unsigned h, unsigned w, float c) {
  f16x2 a = __builtin_bit_cast(f16x2, h);
  f16x2 b = __builtin_bit_cast(f16x2, w);
#if __has_builtin(__builtin_amdgcn_fdot2)
  return __builtin_amdgcn_fdot2(a, b, c, false);
#else
  return fmaf((float)a.x, (float)b.x, fmaf((float)a.y, (float)b.y, c));
#endif
}

__device__ __forceinline__ unsigned packf16(float lo, float hi) {
  f16x2 v = {(_Float16)lo, (_Float16)hi};
  return __builtin_bit_cast(unsigned, v);
}

// ---- bucketed CSR build ----
// bucket = dst >> 8  (256 nodes per bucket)
#define NBKT 391                 // ceil(100000 / 256)
#define NBLK 320                 // partition blocks
#define EPB  (NE / NBLK)         // 5000 edges per partition block (=1250 int4)
#define PTH  512                 // threads in partition/bucket kernels
#define TOT  (NBKT * NBLK)       // 125120 pcount entries
#define SB   ((TOT + 1023) / 1024)  // 123 scan blocks

__global__ __launch_bounds__(PTH) void k_pcount(const int4* __restrict__ dst4,
                                                int* __restrict__ pcount) {
  __shared__ int lcnt[NBKT];
  int t = threadIdx.x, b = blockIdx.x;
  for (int i = t; i < NBKT; i += PTH) lcnt[i] = 0;
  __syncthreads();
  int base4 = b * (EPB / 4);
  for (int i = t; i < EPB / 4; i += PTH) {
    int4 d = dst4[base4 + i];
    atomicAdd(&lcnt[d.x >> 8], 1);
    atomicAdd(&lcnt[d.y >> 8], 1);
    atomicAdd(&lcnt[d.z >> 8], 1);
    atomicAdd(&lcnt[d.w >> 8], 1);
  }
  __syncthreads();
  for (int i = t; i < NBKT; i += PTH)
    pcount[i * NBLK + b] = lcnt[i];   // bucket-major layout
}

// hierarchical exclusive scan of pcount[TOT] (block-local; consumers add bsum)
__global__ __launch_bounds__(256) void k_pscan1(int* __restrict__ pcount,
                                                int* __restrict__ bsum) {
  __shared__ int sh[256];
  int t = threadIdx.x, b = blockIdx.x;
  int base = b * 1024 + t * 4;
  int v0 = (base + 0 < TOT) ? pcount[base + 0] : 0;
  int v1 = (base + 1 < TOT) ? pcount[base + 1] : 0;
  int v2 = (base + 2 < TOT) ? pcount[base + 2] : 0;
  int v3 = (base + 3 < TOT) ? pcount[base + 3] : 0;
  int s = v0 + v1 + v2 + v3;
  sh[t] = s;
  __syncthreads();
  for (int off = 1; off < 256; off <<= 1) {
    int x = (t >= off) ? sh[t - off] : 0;
    __syncthreads();
    sh[t] += x;
    __syncthreads();
  }
  int ex = sh[t] - s;
  if (t == 255) bsum[b] = sh[255];
  if (base + 0 < TOT) pcount[base + 0] = ex; ex += v0;
  if (base + 1 < TOT) pcount[base + 1] = ex; ex += v1;
  if (base + 2 < TOT) pcount[base + 2] = ex; ex += v2;
  if (base + 3 < TOT) pcount[base + 3] = ex;
}

__global__ __launch_bounds__(128) void k_pscan2(int* __restrict__ bsum) {
  __shared__ int sh[128];
  int t = threadIdx.x;
  int v = (t < SB) ? bsum[t] : 0;
  sh[t] = v;
  __syncthreads();
  for (int off = 1; off < 128; off <<= 1) {
    int x = (t >= off) ? sh[t - off] : 0;
    __syncthreads();
    sh[t] += x;
    __syncthreads();
  }
  if (t < SB) bsum[t] = sh[t] - v;  // exclusive
}

__device__ __forceinline__ int pc_at(const int* pcount, const int* bsum, int idx) {
  return pcount[idx] + bsum[idx >> 10];
}

// staged entry packs src (17 bits) | (dst & 255) << 17
__global__ __launch_bounds__(PTH) void k_pscatter(const int4* __restrict__ src4,
                                                  const int4* __restrict__ dst4,
                                                  const int* __restrict__ pcount,
                                                  const int* __restrict__ bsum,
                                                  int* __restrict__ staged) {
  __shared__ int lpos[NBKT];
  int t = threadIdx.x, b = blockIdx.x;
  for (int i = t; i < NBKT; i += PTH)
    lpos[i] = pc_at(pcount, bsum, i * NBLK + b);
  __syncthreads();
  int base4 = b * (EPB / 4);
  for (int i = t; i < EPB / 4; i += PTH) {
    int4 s = src4[base4 + i];
    int4 d = dst4[base4 + i];
    int p0 = atomicAdd(&lpos[d.x >> 8], 1);
    staged[p0] = s.x | ((d.x & 255) << 17);
    int p1 = atomicAdd(&lpos[d.y >> 8], 1);
    staged[p1] = s.y | ((d.y & 255) << 17);
    int p2 = atomicAdd(&lpos[d.z >> 8], 1);
    staged[p2] = s.z | ((d.z & 255) << 17);
    int p3 = atomicAdd(&lpos[d.w >> 8], 1);
    staged[p3] = s.w | ((d.w & 255) << 17);
  }
}

__global__ __launch_bounds__(PTH) void k_bucket(const int* __restrict__ staged,
                                                const int* __restrict__ pcount,
                                                const int* __restrict__ bsum,
                                                int* __restrict__ rowptr,
                                                float* __restrict__ dis,
                                                int* __restrict__ col) {
  __shared__ int lcnt[256];
  __shared__ int lscan[PTH];
  __shared__ int lpos[256];
  int t = threadIdx.x, bkt = blockIdx.x;
  int sbeg = pc_at(pcount, bsum, bkt * NBLK);
  int send = (bkt == NBKT - 1) ? NE : pc_at(pcount, bsum, (bkt + 1) * NBLK);

  if (t < 256) lcnt[t] = 0;
  __syncthreads();
  for (int i = sbeg + t; i < send; i += PTH)
    atomicAdd(&lcnt[(unsigned)staged[i] >> 17], 1);
  __syncthreads();

  int v = (t < 256) ? lcnt[t] : 0;
  lscan[t] = v;
  __syncthreads();
  for (int off = 1; off < PTH; off <<= 1) {
    int x = (t >= off) ? lscan[t - off] : 0;
    __syncthreads();
    lscan[t] += x;
    __syncthreads();
  }
  if (t < 256) {
    int gbase = sbeg + lscan[t] - v;
    int node = bkt * 256 + t;
    if (node < NN) {
      rowptr[node] = gbase;
      dis[node] = rsqrtf((float)(v + 1));  // +1 self-loop
    }
    lpos[t] = gbase;
    if (bkt == NBKT - 1 && t == 0) rowptr[NN] = NE;
  }
  __syncthreads();

  for (int i = sbeg + t; i < send; i += PTH) {
    int e = staged[i];
    col[atomicAdd(&lpos[(unsigned)e >> 17], 1)] = e & 0x1FFFF;
  }
}

__device__ __forceinline__ unsigned bf16rne(float x) {
  unsigned u = __float_as_uint(x);
  return (u + 0x7fffu + ((u >> 16) & 1u)) >> 16;   // round-nearest-even
}

// ---- layer 1 transform: t' = dis * (x @ W), bf16 [NN][64] ----
// f16-dot2 version: x packed as k-pairs transposed hTp[kp][row] (16B-aligned
// rows -> conflict-free b128 reads of 4 rows), W packed Wp[kp][col].
__global__ __launch_bounds__(256) void k_xform(const float* __restrict__ h,
                                               const float* __restrict__ W,
                                               const float* __restrict__ dis,
                                               unsigned short* __restrict__ ts) {
  __shared__ unsigned hTp[32][132];  // [kpair][row]
  __shared__ unsigned Wp[32][72];    // [kpair][col]
  const int tid = threadIdx.x;
  const int R0 = blockIdx.x * 128;

  {
    const float4* W4 = (const float4*)W;
    #pragma unroll
    for (int it = 0; it < 2; ++it) {
      int task = tid + 256 * it;
      int kp = task >> 4;
      int cq = task & 15;
      float4 a = W4[(2 * kp) * 16 + cq];
      float4 b = W4[(2 * kp + 1) * 16 + cq];
      Wp[kp][cq * 4 + 0] = packf16(a.x, b.x);
      Wp[kp][cq * 4 + 1] = packf16(a.y, b.y);
      Wp[kp][cq * 4 + 2] = packf16(a.z, b.z);
      Wp[kp][cq * 4 + 3] = packf16(a.w, b.w);
    }
  }
  {
    #pragma unroll
    for (int j = 0; j < 8; ++j) {
      int idx = tid + 256 * j;
      int r = idx >> 4;
      int kp = (idx & 15) * 2;
      int rg = R0 + r; if (rg > NN - 1) rg = NN - 1;
      float4 v = *(const float4*)(h + (size_t)rg * 64 + kp * 2);
      hTp[kp][r]     = packf16(v.x, v.y);
      hTp[kp + 1][r] = packf16(v.z, v.w);
    }
  }
  __syncthreads();

  const int tx = tid & 7;
  const int ty = tid >> 3;
  float acc[4][8];
  #pragma unroll
  for (int i = 0; i < 4; ++i)
    #pragma unroll
    for (int j = 0; j < 8; ++j) acc[i][j] = 0.f;

  #pragma unroll 4
  for (int kp = 0; kp < 32; ++kp) {
    uint4 hv = *(const uint4*)&hTp[kp][ty * 4];
    uint4 w0 = *(const uint4*)&Wp[kp][tx * 8];
    uint4 w1 = *(const uint4*)&Wp[kp][tx * 8 + 4];
    unsigned hh[4] = {hv.x, hv.y, hv.z, hv.w};
    unsigned wc[8] = {w0.x, w0.y, w0.z, w0.w, w1.x, w1.y, w1.z, w1.w};
    #pragma unroll
    for (int i = 0; i < 4; ++i)
      #pragma unroll
      for (int j = 0; j < 8; ++j)
        acc[i][j] = dot2(hh[i], wc[j], acc[i][j]);
  }

  #pragma unroll
  for (int i = 0; i < 4; ++i) {
    int r = R0 + ty * 4 + i;
    if (r < NN) {
      float dr = dis[r];
      uint4 pk;
      pk.x = bf16rne(acc[i][0] * dr) | (bf16rne(acc[i][1] * dr) << 16);
      pk.y = bf16rne(acc[i][2] * dr) | (bf16rne(acc[i][3] * dr) << 16);
      pk.z = bf16rne(acc[i][4] * dr) | (bf16rne(acc[i][5] * dr) << 16);
      pk.w = bf16rne(acc[i][6] * dr) | (bf16rne(acc[i][7] * dr) << 16);
      *(uint4*)(ts + (size_t)r * 64 + tx * 8) = pk;
    }
  }
}

// ---- fused: h' = relu(dis_d*(S_sum t') + b) ; t_next = dis * (h' @ Wn) ----
// Barrier only after W staging; each wave's phase 2 reads ONLY its own hp
// rows, so gather -> GEMM flows without a block barrier.
__global__ __launch_bounds__(256) void k_fuse(
    const unsigned short* __restrict__ ts, const int* __restrict__ rowptr,
    const int* __restrict__ col, const float* __restrict__ dis,
    const float* __restrict__ bias, const float* __restrict__ Wn,
    unsigned short* __restrict__ tnext)
{
  __shared__ unsigned Wp[32][72];   // [kpair][col] f16 pairs over k
  __shared__ unsigned hp[32][36];   // [row][kpair] f16 pairs
  const int tid  = threadIdx.x;
  const int lane = tid & 63;
  const int slot = lane >> 4;
  const int fq   = lane & 15;
  const int R0   = blockIdx.x * 32;
  const int wloc = tid >> 6;            // wave in block 0..3
  const int wid  = __builtin_amdgcn_readfirstlane(
                     (int)(blockIdx.x * 4 + wloc));
  const int n0   = wid * 8;

  // stage Wn packed: task = (kp, colquad); 512 tasks, 2 per thread
  {
    const float4* W4 = (const float4*)Wn;
    #pragma unroll
    for (int it = 0; it < 2; ++it) {
      int task = tid + 256 * it;        // 0..511
      int kp = task >> 4;               // k-pair 0..31
      int cq = task & 15;               // col quad 0..15
      float4 a = W4[(2 * kp) * 16 + cq];      // row 2kp, cols cq*4..
      float4 b = W4[(2 * kp + 1) * 16 + cq];  // row 2kp+1
      Wp[kp][cq * 4 + 0] = packf16(a.x, b.x);
      Wp[kp][cq * 4 + 1] = packf16(a.y, b.y);
      Wp[kp][cq * 4 + 2] = packf16(a.z, b.z);
      Wp[kp][cq * 4 + 3] = packf16(a.w, b.w);
    }
  }
  __syncthreads();   // Wp ready; the ONLY block barrier

  const float4 bv = *(const float4*)(bias + fq * 4);
  const float m_self = (slot == 0) ? 1.f : 0.f;

  i32x16 rp;
  asm volatile("s_load_dwordx16 %0, %1, 0x0\n\ts_waitcnt lgkmcnt(0)"
               : "=s"(rp) : "s"(rowptr + n0));

  float a[8][4];
  #pragma unroll
  for (int i = 0; i < 8; ++i) {
    const uint2 sv = *(const uint2*)(ts + (size_t)(n0 + i) * 64 + fq * 4);
    a[i][0] = m_self * __uint_as_float(sv.x << 16);
    a[i][1] = m_self * __uint_as_float(sv.x & 0xffff0000u);
    a[i][2] = m_self * __uint_as_float(sv.y << 16);
    a[i][3] = m_self * __uint_as_float(sv.y & 0xffff0000u);
  }

  // phase 1a: first 16 edges of each node, straight-line & masked
  #pragma unroll
  for (int i = 0; i < 8; ++i) {
    const int r0 = rp[i], r1 = rp[i + 1];
    #pragma unroll
    for (int s = 0; s < 4; ++s) {
      int e = r0 + s * 4 + slot;
      int c = col[e];
      bool valid = e < r1;
      c = valid ? c : 0;
      float m = valid ? 1.f : 0.f;
      const uint2 gv = *(const uint2*)(ts + (size_t)c * 64 + fq * 4);
      a[i][0] = fmaf(m, __uint_as_float(gv.x << 16),         a[i][0]);
      a[i][1] = fmaf(m, __uint_as_float(gv.x & 0xffff0000u), a[i][1]);
      a[i][2] = fmaf(m, __uint_as_float(gv.y << 16),         a[i][2]);
      a[i][3] = fmaf(m, __uint_as_float(gv.y & 0xffff0000u), a[i][3]);
    }
  }

  // phase 1b: remainders (deg > 16)
  #pragma unroll
  for (int i = 0; i < 8; ++i) {
    const int r1 = rp[i + 1];
    #pragma unroll 1
    for (int e0 = rp[i] + 16; e0 < r1; e0 += 8) {
      #pragma unroll
      for (int s = 0; s < 2; ++s) {
        int e = e0 + s * 4 + slot;
        int c = col[e];
        bool valid = e < r1;
        c = valid ? c : 0;
        float m = valid ? 1.f : 0.f;
        const uint2 gv = *(const uint2*)(ts + (size_t)c * 64 + fq * 4);
        a[i][0] = fmaf(m, __uint_as_float(gv.x << 16),         a[i][0]);
        a[i][1] = fmaf(m, __uint_as_float(gv.x & 0xffff0000u), a[i][1]);
        a[i][2] = fmaf(m, __uint_as_float(gv.y << 16),         a[i][2]);
        a[i][3] = fmaf(m, __uint_as_float(gv.y & 0xffff0000u), a[i][3]);
      }
    }
  }

  // reduce across slots; h' = relu(dn*s + b) -> hp (this wave's rows only)
  #pragma unroll
  for (int i = 0; i < 8; ++i) {
    const int node = n0 + i;
    const float dn = dis[node];
    float s0 = a[i][0], s1 = a[i][1], s2 = a[i][2], s3 = a[i][3];
    s0 += __shfl_xor(s0, 16); s1 += __shfl_xor(s1, 16);
    s2 += __shfl_xor(s2, 16); s3 += __shfl_xor(s3, 16);
    s0 += __shfl_xor(s0, 32); s1 += __shfl_xor(s1, 32);
    s2 += __shfl_xor(s2, 32); s3 += __shfl_xor(s3, 32);
    float o0 = fmaxf(fmaf(dn, s0, bv.x), 0.f);
    float o1 = fmaxf(fmaf(dn, s1, bv.y), 0.f);
    float o2 = fmaxf(fmaf(dn, s2, bv.z), 0.f);
    float o3 = fmaxf(fmaf(dn, s3, bv.w), 0.f);
    if (lane < 16) {
      uint2 pk = make_uint2(packf16(o0, o1), packf16(o2, o3));
      *(uint2*)&hp[wloc * 8 + i][fq * 2] = pk;
    }
  }
  // NO barrier: wave w's phase 2 reads rows 8w..8w+7, written by itself.

  // phase 2: t_next = dis * (h' @ Wn) via dot2; ty=row, tx=col-group
  const int tx = tid & 7;     // col group (8 cols)
  const int ty = tid >> 3;    // row 0..31
  float acc[8];
  #pragma unroll
  for (int j = 0; j < 8; ++j) acc[j] = 0.f;
  #pragma unroll 4
  for (int kp = 0; kp < 32; ++kp) {
    unsigned hv = hp[ty][kp];
    uint4 w0 = *(const uint4*)&Wp[kp][tx * 8];
    uint4 w1 = *(const uint4*)&Wp[kp][tx * 8 + 4];
    acc[0] = dot2(hv, w0.x, acc[0]); acc[1] = dot2(hv, w0.y, acc[1]);
    acc[2] = dot2(hv, w0.z, acc[2]); acc[3] = dot2(hv, w0.w, acc[3]);
    acc[4] = dot2(hv, w1.x, acc[4]); acc[5] = dot2(hv, w1.y, acc[5]);
    acc[6] = dot2(hv, w1.z, acc[6]); acc[7] = dot2(hv, w1.w, acc[7]);
  }
  {
    int r = R0 + ty;
    float dr = dis[r];
    uint4 pk;
    pk.x = bf16rne(acc[0] * dr) | (bf16rne(acc[1] * dr) << 16);
    pk.y = bf16rne(acc[2] * dr) | (bf16rne(acc[3] * dr) << 16);
    pk.z = bf16rne(acc[4] * dr) | (bf16rne(acc[5] * dr) << 16);
    pk.w = bf16rne(acc[6] * dr) | (bf16rne(acc[7] * dr) << 16);
    *(uint4*)(tnext + (size_t)r * 64 + tx * 8) = pk;
  }
}

// ---- final layer: out = dis_d*(S_sum t') + b  (fp32, no relu) ----
__global__ __launch_bounds__(256) void k_agg(
    const unsigned short* __restrict__ ts, const int* __restrict__ rowptr,
    const int* __restrict__ col, const float* __restrict__ dis,
    const float* __restrict__ bias, float* __restrict__ out)
{
  const int lane = threadIdx.x & 63;
  const int slot = lane >> 4;
  const int fq   = lane & 15;
  const int wid  = __builtin_amdgcn_readfirstlane(
                     (int)((blockIdx.x * blockDim.x + threadIdx.x) >> 6));
  const int n0   = wid * 8;
  if (n0 >= NN) return;

  const float4 bv = *(const float4*)(bias + fq * 4);
  const float m_self = (slot == 0) ? 1.f : 0.f;

  i32x16 rp;
  asm volatile("s_load_dwordx16 %0, %1, 0x0\n\ts_waitcnt lgkmcnt(0)"
               : "=s"(rp) : "s"(rowptr + n0));

  float a[8][4];
  #pragma unroll
  for (int i = 0; i < 8; ++i) {
    const uint2 sv = *(const uint2*)(ts + (size_t)(n0 + i) * 64 + fq * 4);
    a[i][0] = m_self * __uint_as_float(sv.x << 16);
    a[i][1] = m_self * __uint_as_float(sv.x & 0xffff0000u);
    a[i][2] = m_self * __uint_as_float(sv.y << 16);
    a[i][3] = m_self * __uint_as_float(sv.y & 0xffff0000u);
  }

  #pragma unroll
  for (int i = 0; i < 8; ++i) {
    const int r0 = rp[i], r1 = rp[i + 1];
    #pragma unroll
    for (int s = 0; s < 4; ++s) {
      int e = r0 + s * 4 + slot;
      int c = col[e];
      bool valid = e < r1;
      c = valid ? c : 0;
      float m = valid ? 1.f : 0.f;
      const uint2 gv = *(const uint2*)(ts + (size_t)c * 64 + fq * 4);
      a[i][0] = fmaf(m, __uint_as_float(gv.x << 16),         a[i][0]);
      a[i][1] = fmaf(m, __uint_as_float(gv.x & 0xffff0000u), a[i][1]);
      a[i][2] = fmaf(m, __uint_as_float(gv.y << 16),         a[i][2]);
      a[i][3] = fmaf(m, __uint_as_float(gv.y & 0xffff0000u), a[i][3]);
    }
  }

  #pragma unroll
  for (int i = 0; i < 8; ++i) {
    const int r1 = rp[i + 1];
    #pragma unroll 1
    for (int e0 = rp[i] + 16; e0 < r1; e0 += 8) {
      #pragma unroll
      for (int s = 0; s < 2; ++s) {
        int e = e0 + s * 4 + slot;
        int c = col[e];
        bool valid = e < r1;
        c = valid ? c : 0;
        float m = valid ? 1.f : 0.f;
        const uint2 gv = *(const uint2*)(ts + (size_t)c * 64 + fq * 4);
        a[i][0] = fmaf(m, __uint_as_float(gv.x << 16),         a[i][0]);
        a[i][1] = fmaf(m, __uint_as_float(gv.x & 0xffff0000u), a[i][1]);
        a[i][2] = fmaf(m, __uint_as_float(gv.y << 16),         a[i][2]);
        a[i][3] = fmaf(m, __uint_as_float(gv.y & 0xffff0000u), a[i][3]);
      }
    }
  }

  #pragma unroll
  for (int i = 0; i < 8; ++i) {
    const int node = n0 + i;
    const float dn = dis[node];
    float s0 = a[i][0], s1 = a[i][1], s2 = a[i][2], s3 = a[i][3];
    s0 += __shfl_xor(s0, 16); s1 += __shfl_xor(s1, 16);
    s2 += __shfl_xor(s2, 16); s3 += __shfl_xor(s3, 16);
    s0 += __shfl_xor(s0, 32); s1 += __shfl_xor(s1, 32);
    s2 += __shfl_xor(s2, 32); s3 += __shfl_xor(s3, 32);
    float4 o;
    o.x = fmaf(dn, s0, bv.x); o.y = fmaf(dn, s1, bv.y);
    o.z = fmaf(dn, s2, bv.z); o.w = fmaf(dn, s3, bv.w);
    if (lane < 16)
      *(float4*)(out + (size_t)node * 64 + fq * 4) = o;
  }
}

extern "C" void kernel_launch(void* const* d_in, const int* in_sizes, int n_in,
                              void* d_out, int out_size, void* d_ws, size_t ws_size,
                              hipStream_t stream) {
  const float* x  = (const float*)d_in[0];
  const int*   ei = (const int*)d_in[1];
  const float* W1 = (const float*)d_in[2];
  const float* b1 = (const float*)d_in[3];
  const float* W2 = (const float*)d_in[4];
  const float* b2 = (const float*)d_in[5];
  const float* W3 = (const float*)d_in[6];
  const float* b3 = (const float*)d_in[7];
  float* out = (float*)d_out;

  const int* src = ei;        // edge_index[0]
  const int* dst = ei + NE;   // edge_index[1]

  char* ws = (char*)d_ws;
  size_t off = 0;
  auto alloc = [&](size_t bytes) {
    void* p = ws + off;
    off = (off + bytes + 255) & ~(size_t)255;
    return p;
  };
  int*   pcount = (int*)alloc((size_t)TOT * 4);
  int*   bsum   = (int*)alloc((size_t)SB * 4);
  int*   rowptr = (int*)alloc((size_t)(NN + 1 + 16) * 4); // +16: s_load overrun pad
  float* dis    = (float*)alloc((size_t)NN * 4);
  int*   staged = (int*)alloc((size_t)NE * 4);            // packed src|dst8
  int*   col    = (int*)alloc((size_t)(NE + 64) * 4);     // +64: load overrun pad
  unsigned short* tb1 =
      (unsigned short*)alloc((size_t)NN * 64 * 2);        // bf16 [NN][64]
  unsigned short* tb2 =
      (unsigned short*)alloc((size_t)NN * 64 * 2);        // bf16 [NN][64]
  (void)ws_size; (void)in_sizes; (void)n_in; (void)out_size;

  k_pcount  <<<NBLK, PTH, 0, stream>>>((const int4*)dst, pcount);
  k_pscan1  <<<SB, 256, 0, stream>>>(pcount, bsum);
  k_pscan2  <<<1, 128, 0, stream>>>(bsum);
  k_pscatter<<<NBLK, PTH, 0, stream>>>((const int4*)src, (const int4*)dst,
                                       pcount, bsum, staged);
  k_bucket  <<<NBKT, PTH, 0, stream>>>(staged, pcount, bsum, rowptr, dis, col);

  const int XF_BLOCKS = (NN + 127) / 128;   // 782
  const int FB        = NN / 32;            // 3125, exact

  k_xform<<<XF_BLOCKS, 256, 0, stream>>>(x, W1, dis, tb1);
  k_fuse <<<FB, 256, 0, stream>>>(tb1, rowptr, col, dis, b1, W2, tb2);
  k_fuse <<<FB, 256, 0, stream>>>(tb2, rowptr, col, dis, b2, W3, tb1);
  k_agg  <<<FB, 256, 0, stream>>>(tb1, rowptr, col, dis, b3, out);
}